// Round 7
// baseline (207.753 us; speedup 1.0000x reference)
//
#include <hip/hip_runtime.h>

#define NH 16
#define HD 64
#define TSEQ 2048
#define DMODEL 1024

typedef __attribute__((ext_vector_type(8))) short short8;
typedef __attribute__((ext_vector_type(4))) float f32x4;

static __device__ __forceinline__ unsigned short f2bf(float f) {
    unsigned u = __builtin_bit_cast(unsigned, f);
    u += 0x7FFF + ((u >> 16) & 1);
    return (unsigned short)(u >> 16);
}

// packed f32x2 -> bf16x2 (low = a, high = b), single VALU op
static __device__ __forceinline__ unsigned cvtpk(float a, float b) {
    unsigned r;
    asm("v_cvt_pk_bf16_f32 %0, %1, %2" : "=v"(r) : "v"(a), "v"(b));
    return r;
}

// ---------------- cast f32 -> bf16 (vectorized) ----------------
__global__ __launch_bounds__(256) void cast_f32_bf16(const float* __restrict__ src,
                                                     unsigned short* __restrict__ dst, int n4) {
    int i = blockIdx.x * 256 + threadIdx.x;
    if (i >= n4) return;
    float4 v = reinterpret_cast<const float4*>(src)[i];
    ushort4 o;
    o.x = f2bf(v.x); o.y = f2bf(v.y); o.z = f2bf(v.z); o.w = f2bf(v.w);
    reinterpret_cast<ushort4*>(dst)[i] = o;
}

__global__ __launch_bounds__(256) void cast_weights(const float* __restrict__ Wq,
                                                    const float* __restrict__ Wk,
                                                    const float* __restrict__ Wv,
                                                    const float* __restrict__ Wo,
                                                    unsigned short* __restrict__ dq,
                                                    unsigned short* __restrict__ dk,
                                                    unsigned short* __restrict__ dv,
                                                    unsigned short* __restrict__ dwo) {
    int g = blockIdx.x >> 10;
    int i = (blockIdx.x & 1023) * 256 + threadIdx.x;
    const float* s = (g == 0) ? Wq : (g == 1) ? Wk : (g == 2) ? Wv : Wo;
    unsigned short* d = (g == 0) ? dq : (g == 1) ? dk : (g == 2) ? dv : dwo;
    float4 v = reinterpret_cast<const float4*>(s)[i];
    ushort4 o;
    o.x = f2bf(v.x); o.y = f2bf(v.y); o.z = f2bf(v.z); o.w = f2bf(v.w);
    reinterpret_cast<ushort4*>(d)[i] = o;
}

// ============ 8-phase 256x128 GEMM mainloop (T2+T3+T4+T5) ============
// C[256x128] = A[M][1024] * Bt[N][1024]^T, bf16 in, f32 acc.
// 512 threads = 8 waves (2M x 4N), wave-out 128x32 (8x2 fragments).
// LDS: A dbuf 2x[256][64] (64KB) + B 3-ring [128][64] (48KB) = 112KB.
// st_16x32 swizzle both sides: linear gload_lds dest + pre-swizzled global
// source col ^ ((row>>2)&1)<<4; identical XOR on ds_read (rule 21).
// Counted vmcnt(2) once per K-tile (3-deep B ring keeps 2 loads in flight).
static __device__ __forceinline__ void gemm256_mainloop(
    const unsigned short* __restrict__ A, const unsigned short* __restrict__ Bt,
    int m0, int n0, unsigned short* As, unsigned short* Bs, f32x4 acc[8][2]) {
    const int tid = threadIdx.x, lane = tid & 63, w = tid >> 6;
    const int wr = w >> 2, wc = w & 3;
    const int lg = lane >> 4, ll = lane & 15;
    const int srow = tid >> 3;          // 0..63
    const int scol8 = (tid & 7) * 8;    // ushort col 0..56

    const f32x4 zero = {0.f, 0.f, 0.f, 0.f};
#pragma unroll
    for (int i = 0; i < 8; i++)
#pragma unroll
        for (int j = 0; j < 2; j++) acc[i][j] = zero;

    auto stageA2 = [&](int kt, int buf, int h) {   // 2 loads: A rows [h*128, h*128+128)
#pragma unroll
        for (int s = h * 2; s < h * 2 + 2; ++s) {
            int row = s * 64 + srow;
            int csw = scol8 ^ (((row >> 2) & 1) << 4);
            __builtin_amdgcn_global_load_lds(
                (const __attribute__((address_space(1))) void*)(A + (size_t)(m0 + row) * DMODEL + kt * 64 + csw),
                (__attribute__((address_space(3))) void*)(As + buf * 16384 + s * 4096 + w * 512), 16, 0, 0);
        }
    };
    auto stageB1 = [&](int kt, int buf, int s) {   // 1 load: B rows [s*64, s*64+64)
        int row = s * 64 + srow;
        int csw = scol8 ^ (((row >> 2) & 1) << 4);
        __builtin_amdgcn_global_load_lds(
            (const __attribute__((address_space(1))) void*)(Bt + (size_t)(n0 + row) * DMODEL + kt * 64 + csw),
            (__attribute__((address_space(3))) void*)(Bs + buf * 8192 + s * 4096 + w * 512), 16, 0, 0);
    };
    auto ldA = [&](int buf, int row, int ks) -> short8 {
        int col = (ks * 32 + lg * 8) ^ (((row >> 2) & 1) << 4);
        return *(const short8*)(As + buf * 16384 + row * 64 + col);
    };
    auto ldB = [&](int buf, int row, int ks) -> short8 {
        int col = (ks * 32 + lg * 8) ^ (((row >> 2) & 1) << 4);
        return *(const short8*)(Bs + buf * 8192 + row * 64 + col);
    };

    // prologue: tile0 A+B, tile1 B; wait tile0 (2 newer B(1) loads stay in flight)
    stageA2(0, 0, 0); stageA2(0, 0, 1);
    stageB1(0, 0, 0); stageB1(0, 0, 1);
    stageB1(1, 1, 0); stageB1(1, 1, 1);
    asm volatile("s_waitcnt vmcnt(2)" ::: "memory");
    __builtin_amdgcn_s_barrier();
    __builtin_amdgcn_sched_barrier(0);

#pragma unroll 1
    for (int kt = 0; kt < 16; ++kt) {
        const int pa = kt & 1;
        const int pb = kt % 3;
        short8 bfr[2][2];
        short8 afr[2][2];

        // ---- phase 0: B frags + A q0; stage A(kt+1) half0 ----
#pragma unroll
        for (int j = 0; j < 2; j++)
#pragma unroll
            for (int ks = 0; ks < 2; ks++)
                bfr[j][ks] = ldB(pb, wc * 32 + j * 16 + ll, ks);
#pragma unroll
        for (int i2 = 0; i2 < 2; i2++)
#pragma unroll
            for (int ks = 0; ks < 2; ks++)
                afr[i2][ks] = ldA(pa, wr * 128 + i2 * 16 + ll, ks);
        if (kt + 1 < 16) stageA2(kt + 1, pa ^ 1, 0);
        __builtin_amdgcn_s_barrier();
        __builtin_amdgcn_sched_barrier(0);
        __builtin_amdgcn_s_setprio(1);
#pragma unroll
        for (int i2 = 0; i2 < 2; i2++)
#pragma unroll
            for (int j = 0; j < 2; j++) {
                acc[i2][j] = __builtin_amdgcn_mfma_f32_16x16x32_bf16(afr[i2][0], bfr[j][0], acc[i2][j], 0, 0, 0);
                acc[i2][j] = __builtin_amdgcn_mfma_f32_16x16x32_bf16(afr[i2][1], bfr[j][1], acc[i2][j], 0, 0, 0);
            }
        __builtin_amdgcn_s_setprio(0);
        __builtin_amdgcn_s_barrier();
        __builtin_amdgcn_sched_barrier(0);

        // ---- phase 1: A q1; stage A(kt+1) half1 ----
#pragma unroll
        for (int i2 = 0; i2 < 2; i2++)
#pragma unroll
            for (int ks = 0; ks < 2; ks++)
                afr[i2][ks] = ldA(pa, wr * 128 + (2 + i2) * 16 + ll, ks);
        if (kt + 1 < 16) stageA2(kt + 1, pa ^ 1, 1);
        __builtin_amdgcn_s_barrier();
        __builtin_amdgcn_sched_barrier(0);
        __builtin_amdgcn_s_setprio(1);
#pragma unroll
        for (int i2 = 0; i2 < 2; i2++)
#pragma unroll
            for (int j = 0; j < 2; j++) {
                acc[2 + i2][j] = __builtin_amdgcn_mfma_f32_16x16x32_bf16(afr[i2][0], bfr[j][0], acc[2 + i2][j], 0, 0, 0);
                acc[2 + i2][j] = __builtin_amdgcn_mfma_f32_16x16x32_bf16(afr[i2][1], bfr[j][1], acc[2 + i2][j], 0, 0, 0);
            }
        __builtin_amdgcn_s_setprio(0);
        __builtin_amdgcn_s_barrier();
        __builtin_amdgcn_sched_barrier(0);

        // ---- phase 2: A q2; stage B(kt+2) part0 ----
#pragma unroll
        for (int i2 = 0; i2 < 2; i2++)
#pragma unroll
            for (int ks = 0; ks < 2; ks++)
                afr[i2][ks] = ldA(pa, wr * 128 + (4 + i2) * 16 + ll, ks);
        if (kt + 2 < 16) stageB1(kt + 2, (kt + 2) % 3, 0);
        __builtin_amdgcn_s_barrier();
        __builtin_amdgcn_sched_barrier(0);
        __builtin_amdgcn_s_setprio(1);
#pragma unroll
        for (int i2 = 0; i2 < 2; i2++)
#pragma unroll
            for (int j = 0; j < 2; j++) {
                acc[4 + i2][j] = __builtin_amdgcn_mfma_f32_16x16x32_bf16(afr[i2][0], bfr[j][0], acc[4 + i2][j], 0, 0, 0);
                acc[4 + i2][j] = __builtin_amdgcn_mfma_f32_16x16x32_bf16(afr[i2][1], bfr[j][1], acc[4 + i2][j], 0, 0, 0);
            }
        __builtin_amdgcn_s_setprio(0);
        __builtin_amdgcn_s_barrier();
        __builtin_amdgcn_sched_barrier(0);

        // ---- phase 3: A q3; stage B(kt+2) part1; tile-boundary counted wait ----
#pragma unroll
        for (int i2 = 0; i2 < 2; i2++)
#pragma unroll
            for (int ks = 0; ks < 2; ks++)
                afr[i2][ks] = ldA(pa, wr * 128 + (6 + i2) * 16 + ll, ks);
        if (kt + 2 < 16) {
            stageB1(kt + 2, (kt + 2) % 3, 1);
            asm volatile("s_waitcnt vmcnt(2)" ::: "memory");   // A(kt+1)+B(kt+1) landed; B(kt+2) in flight
        } else {
            asm volatile("s_waitcnt vmcnt(0)" ::: "memory");   // tail: drain
        }
        __builtin_amdgcn_s_barrier();
        __builtin_amdgcn_sched_barrier(0);
        __builtin_amdgcn_s_setprio(1);
#pragma unroll
        for (int i2 = 0; i2 < 2; i2++)
#pragma unroll
            for (int j = 0; j < 2; j++) {
                acc[6 + i2][j] = __builtin_amdgcn_mfma_f32_16x16x32_bf16(afr[i2][0], bfr[j][0], acc[6 + i2][j], 0, 0, 0);
                acc[6 + i2][j] = __builtin_amdgcn_mfma_f32_16x16x32_bf16(afr[i2][1], bfr[j][1], acc[6 + i2][j], 0, 0, 0);
            }
        __builtin_amdgcn_s_setprio(0);
        __builtin_amdgcn_s_barrier();
        __builtin_amdgcn_sched_barrier(0);
    }
}

// ---------------- QKV projection (8-phase) ----------------
#define QSCALE 0.180336880f
__global__ __launch_bounds__(512) void gemm_qkv(const unsigned short* __restrict__ xb,
                                                const unsigned short* __restrict__ Wqb,
                                                const unsigned short* __restrict__ Wkb,
                                                const unsigned short* __restrict__ Wvb,
                                                unsigned short* __restrict__ Q,
                                                unsigned short* __restrict__ K,
                                                unsigned short* __restrict__ Vt) {
    __shared__ __attribute__((aligned(16))) unsigned short As[2 * 256 * 64];
    __shared__ __attribute__((aligned(16))) unsigned short Bs[3 * 128 * 64];
    const int m0 = blockIdx.x * 256;
    const int n0 = blockIdx.y * 128;
    const int z = blockIdx.z;
    const unsigned short* Bt = (z == 0) ? Wqb : ((z == 1) ? Wkb : Wvb);
    unsigned short* out = (z == 0) ? Q : ((z == 1) ? K : Vt);

    f32x4 acc[8][2];
    gemm256_mainloop(xb, Bt, m0, n0, As, Bs, acc);

    const int lane = threadIdx.x & 63, w = threadIdx.x >> 6;
    const int wr = w >> 2, wc = w & 3;
    const int lg = lane >> 4, ll = lane & 15;
    const float sc = (z == 0) ? QSCALE : 1.0f;
#pragma unroll
    for (int i = 0; i < 8; i++)
#pragma unroll
        for (int j = 0; j < 2; j++)
#pragma unroll
            for (int r = 0; r < 4; r++) {
                int row = m0 + wr * 128 + i * 16 + lg * 4 + r;  // b*2048 + t
                int col = n0 + wc * 32 + j * 16 + ll;           // h*64 + d
                int b = row >> 11, t = row & 2047;
                int h = col >> 6, d = col & 63;
                unsigned short v = f2bf(acc[i][j][r] * sc);
                if (z == 2)
                    out[(((size_t)(b * NH + h)) * HD + d) * TSEQ + t] = v;
                else
                    out[(((size_t)(b * NH + h)) * TSEQ + t) * HD + d] = v;
            }
}

// ---------------- output projection (8-phase) ----------------
__global__ __launch_bounds__(512) void gemm_out(const unsigned short* __restrict__ ctx,
                                                const unsigned short* __restrict__ Wob,
                                                const float* __restrict__ bo,
                                                float* __restrict__ out) {
    __shared__ __attribute__((aligned(16))) unsigned short As[2 * 256 * 64];
    __shared__ __attribute__((aligned(16))) unsigned short Bs[3 * 128 * 64];
    const int m0 = blockIdx.x * 256;
    const int n0 = blockIdx.y * 128;

    f32x4 acc[8][2];
    gemm256_mainloop(ctx, Wob, m0, n0, As, Bs, acc);

    const int lane = threadIdx.x & 63, w = threadIdx.x >> 6;
    const int wr = w >> 2, wc = w & 3;
    const int lg = lane >> 4, ll = lane & 15;
#pragma unroll
    for (int i = 0; i < 8; i++)
#pragma unroll
        for (int j = 0; j < 2; j++) {
            int col = n0 + wc * 32 + j * 16 + ll;
            float bias = bo[col];
#pragma unroll
            for (int r = 0; r < 4; r++) {
                int row = m0 + wr * 128 + i * 16 + lg * 4 + r;
                out[(size_t)row * DMODEL + col] = acc[i][j][r] + bias;
            }
        }
}

// ---------------- flash attention (causal), Q-tile 128, KV-tile 64, 4 waves ----------------
// S^T structure: st = mfma(K, Q) so q = lane&15 (lane-local rows), k = cb*16+4*lg+r.
// Softmax in-register + 2 shfl. P packed via v_cvt_pk_bf16_f32, b64 LDS writes.
// PV computed as O^T = mfma(Vt-frag, P-frag). Raw s_barrier pipeline (T4).
__global__ __launch_bounds__(256) void attn(const unsigned short* __restrict__ Qg,
                                            const unsigned short* __restrict__ Kg,
                                            const unsigned short* __restrict__ Vg,
                                            unsigned short* __restrict__ ctx) {
    __shared__ __attribute__((aligned(16))) unsigned short Ks[64][72];
    __shared__ __attribute__((aligned(16))) unsigned short Vs[64][72];
    __shared__ __attribute__((aligned(16))) unsigned short Pl[128][76];

    const int tid = threadIdx.x, lane = tid & 63, w = tid >> 6;
    const int wq = w * 32;
    const int lg = lane >> 4;
    const int ll = lane & 15;
    const int bh = blockIdx.x;
    const int q0 = (gridDim.y - 1 - blockIdx.y) * 128;   // heavy tiles first (LPT)
    const unsigned short* Qh = Qg + (size_t)bh * TSEQ * HD;
    const unsigned short* Kh = Kg + (size_t)bh * TSEQ * HD;
    const unsigned short* Vh = Vg + (size_t)bh * HD * TSEQ;

    short8 qf[2][2];
#pragma unroll
    for (int rb = 0; rb < 2; rb++)
#pragma unroll
        for (int ks = 0; ks < 2; ks++)
            qf[rb][ks] = *(const short8*)(Qh + (size_t)(q0 + wq + rb * 16 + ll) * HD + ks * 32 + lg * 8);

    float mrun[2] = {-1e30f, -1e30f}, lrun[2] = {0.f, 0.f};
    const f32x4 zerov = {0.f, 0.f, 0.f, 0.f};
    f32x4 o_t[2][4];
#pragma unroll
    for (int rb = 0; rb < 2; rb++)
#pragma unroll
        for (int db = 0; db < 4; db++) o_t[rb][db] = zerov;

    const int sr = tid >> 3;
    const int sc = (tid & 7) * 8;
    short8 kreg0, kreg1, vreg0, vreg1;
    {
        kreg0 = *(const short8*)(Kh + (size_t)(sr) * HD + sc);
        kreg1 = *(const short8*)(Kh + (size_t)(sr + 32) * HD + sc);
        vreg0 = *(const short8*)(Vh + (size_t)sr * TSEQ + sc);
        vreg1 = *(const short8*)(Vh + (size_t)(sr + 32) * TSEQ + sc);
    }

    const int nkv = q0 / 64 + 2;
    for (int kt = 0; kt < nkv; kt++) {
        const int kv0 = kt * 64;
        __builtin_amdgcn_s_barrier();
        __builtin_amdgcn_sched_barrier(0);
        *(short8*)&Ks[sr][sc] = kreg0;
        *(short8*)&Ks[sr + 32][sc] = kreg1;
        *(short8*)&Vs[sr][sc] = vreg0;
        *(short8*)&Vs[sr + 32][sc] = vreg1;
        if (kt + 1 < nkv) {
            const int nv0 = kv0 + 64;
            kreg0 = *(const short8*)(Kh + (size_t)(nv0 + sr) * HD + sc);
            kreg1 = *(const short8*)(Kh + (size_t)(nv0 + sr + 32) * HD + sc);
            vreg0 = *(const short8*)(Vh + (size_t)sr * TSEQ + nv0 + sc);
            vreg1 = *(const short8*)(Vh + (size_t)(sr + 32) * TSEQ + nv0 + sc);
        }
        __builtin_amdgcn_sched_barrier(0);
        asm volatile("s_waitcnt lgkmcnt(0)" ::: "memory");
        __builtin_amdgcn_s_barrier();
        __builtin_amdgcn_sched_barrier(0);

        short8 af0[4], af1[4];
#pragma unroll
        for (int cb = 0; cb < 4; cb++) {
            af0[cb] = *(const short8*)&Ks[cb * 16 + ll][lg * 8];
            af1[cb] = *(const short8*)&Ks[cb * 16 + ll][32 + lg * 8];
        }
        f32x4 st[2][4];
#pragma unroll
        for (int rb = 0; rb < 2; rb++)
#pragma unroll
            for (int cb = 0; cb < 4; cb++)
                st[rb][cb] = __builtin_amdgcn_mfma_f32_16x16x32_bf16(af0[cb], qf[rb][0], zerov, 0, 0, 0);
#pragma unroll
        for (int rb = 0; rb < 2; rb++)
#pragma unroll
            for (int cb = 0; cb < 4; cb++)
                st[rb][cb] = __builtin_amdgcn_mfma_f32_16x16x32_bf16(af1[cb], qf[rb][1], st[rb][cb], 0, 0, 0);

        if (kv0 + 63 > q0) {
#pragma unroll
            for (int rb = 0; rb < 2; rb++)
#pragma unroll
                for (int cb = 0; cb < 4; cb++)
#pragma unroll
                    for (int r = 0; r < 4; r++) {
                        int kvl = cb * 16 + lg * 4 + r;
                        int ql = wq + rb * 16 + ll;
                        if (kv0 + kvl > q0 + ql) st[rb][cb][r] = -1e30f;
                    }
        }

        float mx[2];
#pragma unroll
        for (int rb = 0; rb < 2; rb++) {
            float a0 = fmaxf(fmaxf(st[rb][0][0], st[rb][0][1]), fmaxf(st[rb][0][2], st[rb][0][3]));
            float a1 = fmaxf(fmaxf(st[rb][1][0], st[rb][1][1]), fmaxf(st[rb][1][2], st[rb][1][3]));
            float a2 = fmaxf(fmaxf(st[rb][2][0], st[rb][2][1]), fmaxf(st[rb][2][2], st[rb][2][3]));
            float a3 = fmaxf(fmaxf(st[rb][3][0], st[rb][3][1]), fmaxf(st[rb][3][2], st[rb][3][3]));
            float m = fmaxf(fmaxf(a0, a1), fmaxf(a2, a3));
            m = fmaxf(m, __shfl_xor(m, 16));
            m = fmaxf(m, __shfl_xor(m, 32));
            mx[rb] = m;
        }
        float need = fmaxf(mx[0] - mrun[0], mx[1] - mrun[1]);
        if (__any(need > 8.f)) {
#pragma unroll
            for (int rb = 0; rb < 2; rb++) {
                float mold = mrun[rb];
                float mn = fmaxf(mold, mx[rb]);
                float rs = __builtin_amdgcn_exp2f(mold - mn);
                mrun[rb] = mn;
                lrun[rb] *= rs;
#pragma unroll
                for (int db = 0; db < 4; db++)
#pragma unroll
                    for (int r = 0; r < 4; r++) o_t[rb][db][r] *= rs;
            }
        }
#pragma unroll
        for (int rb = 0; rb < 2; rb++) {
            float sum = 0.f;
#pragma unroll
            for (int cb = 0; cb < 4; cb++) {
                float p0 = __builtin_amdgcn_exp2f(st[rb][cb][0] - mrun[rb]);
                float p1 = __builtin_amdgcn_exp2f(st[rb][cb][1] - mrun[rb]);
                float p2 = __builtin_amdgcn_exp2f(st[rb][cb][2] - mrun[rb]);
                float p3 = __builtin_amdgcn_exp2f(st[rb][cb][3] - mrun[rb]);
                sum += (p0 + p1) + (p2 + p3);
                uint2 pw;
                pw.x = cvtpk(p0, p1);
                pw.y = cvtpk(p2, p3);
                *(uint2*)&Pl[wq + rb * 16 + ll][cb * 16 + lg * 4] = pw;
            }
            sum += __shfl_xor(sum, 16);
            sum += __shfl_xor(sum, 32);
            lrun[rb] += sum;
        }
        asm volatile("s_waitcnt lgkmcnt(0)" ::: "memory");
        __builtin_amdgcn_sched_barrier(0);

#pragma unroll
        for (int ks = 0; ks < 2; ks++) {
            short8 pa[2], va[4];
#pragma unroll
            for (int rb = 0; rb < 2; rb++)
                pa[rb] = *(const short8*)&Pl[wq + rb * 16 + ll][ks * 32 + lg * 8];
#pragma unroll
            for (int db = 0; db < 4; db++)
                va[db] = *(const short8*)&Vs[db * 16 + ll][ks * 32 + lg * 8];
#pragma unroll
            for (int rb = 0; rb < 2; rb++)
#pragma unroll
                for (int db = 0; db < 4; db++)
                    o_t[rb][db] = __builtin_amdgcn_mfma_f32_16x16x32_bf16(va[db], pa[rb], o_t[rb][db], 0, 0, 0);
        }
    }

    const int b = bh >> 4, h = bh & 15;
#pragma unroll
    for (int rb = 0; rb < 2; rb++) {
        float linv = 1.f / lrun[rb];
#pragma unroll
        for (int db = 0; db < 4; db++) {
            uint2 pw;
            pw.x = cvtpk(o_t[rb][db][0] * linv, o_t[rb][db][1] * linv);
            pw.y = cvtpk(o_t[rb][db][2] * linv, o_t[rb][db][3] * linv);
            *(uint2*)&Pl[wq + rb * 16 + ll][db * 16 + lg * 4] = pw;
        }
    }
    asm volatile("s_waitcnt lgkmcnt(0)" ::: "memory");
    __builtin_amdgcn_sched_barrier(0);
#pragma unroll
    for (int rb = 0; rb < 2; rb++)
#pragma unroll
        for (int half = 0; half < 2; half++) {
            short8 v = *(const short8*)&Pl[wq + rb * 16 + ll][half * 32 + lg * 8];
            size_t row = (size_t)(b * TSEQ + q0 + wq + rb * 16 + ll);
            *(short8*)(ctx + (row * NH + h) * HD + half * 32 + lg * 8) = v;
        }
}

extern "C" void kernel_launch(void* const* d_in, const int* in_sizes, int n_in,
                              void* d_out, int out_size, void* d_ws, size_t ws_size,
                              hipStream_t stream) {
    const float* x  = (const float*)d_in[0];
    const float* Wq = (const float*)d_in[1];
    const float* Wk = (const float*)d_in[2];
    const float* Wv = (const float*)d_in[3];
    const float* Wo = (const float*)d_in[4];
    const float* bo = (const float*)d_in[5];
    float* out = (float*)d_out;

    char* ws = (char*)d_ws;
    unsigned short* xb   = (unsigned short*)(ws);             // 16,777,216 B
    unsigned short* Wqb  = (unsigned short*)(ws + 16777216);
    unsigned short* Wkb  = (unsigned short*)(ws + 18874368);
    unsigned short* Wvb  = (unsigned short*)(ws + 20971520);
    unsigned short* Wob  = (unsigned short*)(ws + 23068672);
    unsigned short* Qb   = (unsigned short*)(ws + 25165824);  // [B,H,T,hd] bf16 (pre-scaled)
    unsigned short* Kb   = (unsigned short*)(ws + 41943040);  // [B,H,T,hd]
    unsigned short* Vtb  = (unsigned short*)(ws + 58720256);  // [B,H,hd,T]
    unsigned short* ctxb = (unsigned short*)(ws + 75497472);  // [B,T,H,hd]

    cast_f32_bf16<<<8192, 256, 0, stream>>>(x, xb, 2097152);
    cast_weights<<<4096, 256, 0, stream>>>(Wq, Wk, Wv, Wo, Wqb, Wkb, Wvb, Wob);

    gemm_qkv<<<dim3(32, 8, 3), 512, 0, stream>>>(xb, Wqb, Wkb, Wvb, Qb, Kb, Vtb);
    attn<<<dim3(64, 16), 256, 0, stream>>>(Qb, Kb, Vtb, ctxb);
    gemm_out<<<dim3(32, 8), 512, 0, stream>>>(ctxb, Wob, bo, out);
}

// Round 8
// 200.006 us; speedup vs baseline: 1.0387x; 1.0387x over previous
//
#include <hip/hip_runtime.h>

#define NH 16
#define HD 64
#define TSEQ 2048
#define DMODEL 1024

typedef __attribute__((ext_vector_type(8))) short short8;
typedef __attribute__((ext_vector_type(4))) float f32x4;

static __device__ __forceinline__ unsigned short f2bf(float f) {
    unsigned u = __builtin_bit_cast(unsigned, f);
    u += 0x7FFF + ((u >> 16) & 1);
    return (unsigned short)(u >> 16);
}

// packed f32x2 -> bf16x2 (low = a, high = b), single VALU op
static __device__ __forceinline__ unsigned cvtpk(float a, float b) {
    unsigned r;
    asm("v_cvt_pk_bf16_f32 %0, %1, %2" : "=v"(r) : "v"(a), "v"(b));
    return r;
}

// ---------------- cast f32 -> bf16 (vectorized) ----------------
__global__ __launch_bounds__(256) void cast_f32_bf16(const float* __restrict__ src,
                                                     unsigned short* __restrict__ dst, int n4) {
    int i = blockIdx.x * 256 + threadIdx.x;
    if (i >= n4) return;
    float4 v = reinterpret_cast<const float4*>(src)[i];
    ushort4 o;
    o.x = f2bf(v.x); o.y = f2bf(v.y); o.z = f2bf(v.z); o.w = f2bf(v.w);
    reinterpret_cast<ushort4*>(dst)[i] = o;
}

__global__ __launch_bounds__(256) void cast_weights(const float* __restrict__ Wq,
                                                    const float* __restrict__ Wk,
                                                    const float* __restrict__ Wv,
                                                    const float* __restrict__ Wo,
                                                    unsigned short* __restrict__ dq,
                                                    unsigned short* __restrict__ dk,
                                                    unsigned short* __restrict__ dv,
                                                    unsigned short* __restrict__ dwo) {
    int g = blockIdx.x >> 10;
    int i = (blockIdx.x & 1023) * 256 + threadIdx.x;
    const float* s = (g == 0) ? Wq : (g == 1) ? Wk : (g == 2) ? Wv : Wo;
    unsigned short* d = (g == 0) ? dq : (g == 1) ? dk : (g == 2) ? dv : dwo;
    float4 v = reinterpret_cast<const float4*>(s)[i];
    ushort4 o;
    o.x = f2bf(v.x); o.y = f2bf(v.y); o.z = f2bf(v.z); o.w = f2bf(v.w);
    reinterpret_cast<ushort4*>(d)[i] = o;
}

// ============ 256x128 GEMM mainloop: 2 phases/K-tile, 16-MFMA clusters ============
// C[256x128] = A[M][1024] * Bt[N][1024]^T, bf16 in, f32 acc.
// 512 threads = 8 waves (4M x 2N), per-wave output 64x64 (acc 4x4) -> 8 ds_read
// + 16 MFMA per phase (ratio 2.0, m201-like). LDS: A dbuf 2x[256][64] (64KB) +
// B 3-ring [128][64] (48KB) = 112KB. Full-strength XOR swizzle (rule 21):
// linear gload_lds dest + source col ^ ((row&7)<<3) + same XOR on ds_read ->
// 16 same-col rows hit 8 distinct 16B slots (2-way = free). Counted vmcnt(2)
// once per K-tile; setprio(1) around MFMA clusters.
static __device__ __forceinline__ void gemm256_mainloop(
    const unsigned short* __restrict__ A, const unsigned short* __restrict__ Bt,
    int m0, int n0, unsigned short* As, unsigned short* Bs, f32x4 acc[4][4]) {
    const int tid = threadIdx.x, lane = tid & 63, w = tid >> 6;
    const int wr = w >> 1, wc = w & 1;
    const int lg = lane >> 4, ll = lane & 15;
    const int strow = tid >> 3;                      // staging row within 64-row slab family
    const int csw = ((tid & 7) * 8) ^ ((strow & 7) << 3);   // pre-swizzled source col
    const int axor = (ll & 7) << 3;                  // read-side XOR

    const f32x4 zero = {0.f, 0.f, 0.f, 0.f};
#pragma unroll
    for (int i = 0; i < 4; i++)
#pragma unroll
        for (int j = 0; j < 4; j++) acc[i][j] = zero;

    auto stageA = [&](int kt, int buf, int half) {   // 2 loads: A rows [half*128, half*128+128)
#pragma unroll
        for (int s = half * 2; s < half * 2 + 2; ++s) {
            int row = s * 64 + strow;
            __builtin_amdgcn_global_load_lds(
                (const __attribute__((address_space(1))) void*)(A + (size_t)(m0 + row) * DMODEL + kt * 64 + csw),
                (__attribute__((address_space(3))) void*)(As + buf * 16384 + s * 4096 + w * 512), 16, 0, 0);
        }
    };
    auto stageB = [&](int kt, int buf) {             // 2 loads: all 128 B rows
#pragma unroll
        for (int s = 0; s < 2; ++s) {
            int row = s * 64 + strow;
            __builtin_amdgcn_global_load_lds(
                (const __attribute__((address_space(1))) void*)(Bt + (size_t)(n0 + row) * DMODEL + kt * 64 + csw),
                (__attribute__((address_space(3))) void*)(Bs + buf * 8192 + s * 4096 + w * 512), 16, 0, 0);
        }
    };

    // prologue: A(0) 4 + B(0) 2 + B(1) 2; wait all but B(1)'s 2
    stageA(0, 0, 0); stageA(0, 0, 1);
    stageB(0, 0); stageB(1, 1);
    asm volatile("s_waitcnt vmcnt(2)" ::: "memory");
    __builtin_amdgcn_s_barrier();
    __builtin_amdgcn_sched_barrier(0);

#pragma unroll 1
    for (int kt = 0; kt < 16; ++kt) {
        const int pa = kt & 1;
        const int pb = kt % 3;

        // ---- phase 0 (ks=0): 8 ds_read + stage A(kt+1) half0 + 16 MFMA ----
        {
            short8 af[4], bf[4];
#pragma unroll
            for (int i = 0; i < 4; i++)
                af[i] = *(const short8*)(As + pa * 16384 + (wr * 64 + i * 16 + ll) * 64 + ((lg * 8) ^ axor));
#pragma unroll
            for (int j = 0; j < 4; j++)
                bf[j] = *(const short8*)(Bs + pb * 8192 + (wc * 64 + j * 16 + ll) * 64 + ((lg * 8) ^ axor));
            if (kt + 1 < 16) stageA(kt + 1, pa ^ 1, 0);
            __builtin_amdgcn_s_barrier();
            __builtin_amdgcn_sched_barrier(0);
            __builtin_amdgcn_s_setprio(1);
#pragma unroll
            for (int i = 0; i < 4; i++)
#pragma unroll
                for (int j = 0; j < 4; j++)
                    acc[i][j] = __builtin_amdgcn_mfma_f32_16x16x32_bf16(af[i], bf[j], acc[i][j], 0, 0, 0);
            __builtin_amdgcn_s_setprio(0);
            __builtin_amdgcn_s_barrier();
            __builtin_amdgcn_sched_barrier(0);
        }

        // ---- phase 1 (ks=1): 8 ds_read + stage A(kt+1) half1 + B(kt+2) + vmcnt + 16 MFMA ----
        {
            short8 af[4], bf[4];
#pragma unroll
            for (int i = 0; i < 4; i++)
                af[i] = *(const short8*)(As + pa * 16384 + (wr * 64 + i * 16 + ll) * 64 + ((32 + lg * 8) ^ axor));
#pragma unroll
            for (int j = 0; j < 4; j++)
                bf[j] = *(const short8*)(Bs + pb * 8192 + (wc * 64 + j * 16 + ll) * 64 + ((32 + lg * 8) ^ axor));
            if (kt + 1 < 16) stageA(kt + 1, pa ^ 1, 1);
            if (kt + 2 < 16) {
                stageB(kt + 2, (kt + 2) % 3);
                asm volatile("s_waitcnt vmcnt(2)" ::: "memory");  // A(kt+1)+B(kt+1) landed; B(kt+2) in flight
            } else {
                asm volatile("s_waitcnt vmcnt(0)" ::: "memory");  // tail drain
            }
            __builtin_amdgcn_s_barrier();
            __builtin_amdgcn_sched_barrier(0);
            __builtin_amdgcn_s_setprio(1);
#pragma unroll
            for (int i = 0; i < 4; i++)
#pragma unroll
                for (int j = 0; j < 4; j++)
                    acc[i][j] = __builtin_amdgcn_mfma_f32_16x16x32_bf16(af[i], bf[j], acc[i][j], 0, 0, 0);
            __builtin_amdgcn_s_setprio(0);
            __builtin_amdgcn_s_barrier();
            __builtin_amdgcn_sched_barrier(0);
        }
    }
}

// ---------------- QKV projection ----------------
#define QSCALE 0.180336880f
__global__ __launch_bounds__(512) void gemm_qkv(const unsigned short* __restrict__ xb,
                                                const unsigned short* __restrict__ Wqb,
                                                const unsigned short* __restrict__ Wkb,
                                                const unsigned short* __restrict__ Wvb,
                                                unsigned short* __restrict__ Q,
                                                unsigned short* __restrict__ K,
                                                unsigned short* __restrict__ Vt) {
    __shared__ __attribute__((aligned(16))) unsigned short As[2 * 256 * 64];
    __shared__ __attribute__((aligned(16))) unsigned short Bs[3 * 128 * 64];
    const int m0 = blockIdx.x * 256;
    const int n0 = blockIdx.y * 128;
    const int z = blockIdx.z;
    const unsigned short* Bt = (z == 0) ? Wqb : ((z == 1) ? Wkb : Wvb);
    unsigned short* out = (z == 0) ? Q : ((z == 1) ? K : Vt);

    f32x4 acc[4][4];
    gemm256_mainloop(xb, Bt, m0, n0, As, Bs, acc);

    const int lane = threadIdx.x & 63, w = threadIdx.x >> 6;
    const int wr = w >> 1, wc = w & 1;
    const int lg = lane >> 4, ll = lane & 15;
    const float sc = (z == 0) ? QSCALE : 1.0f;
#pragma unroll
    for (int i = 0; i < 4; i++)
#pragma unroll
        for (int j = 0; j < 4; j++)
#pragma unroll
            for (int r = 0; r < 4; r++) {
                int row = m0 + wr * 64 + i * 16 + lg * 4 + r;   // b*2048 + t
                int col = n0 + wc * 64 + j * 16 + ll;           // h*64 + d
                int b = row >> 11, t = row & 2047;
                int h = col >> 6, d = col & 63;
                unsigned short v = f2bf(acc[i][j][r] * sc);
                if (z == 2)
                    out[(((size_t)(b * NH + h)) * HD + d) * TSEQ + t] = v;
                else
                    out[(((size_t)(b * NH + h)) * TSEQ + t) * HD + d] = v;
            }
}

// ---------------- output projection ----------------
__global__ __launch_bounds__(512) void gemm_out(const unsigned short* __restrict__ ctx,
                                                const unsigned short* __restrict__ Wob,
                                                const float* __restrict__ bo,
                                                float* __restrict__ out) {
    __shared__ __attribute__((aligned(16))) unsigned short As[2 * 256 * 64];
    __shared__ __attribute__((aligned(16))) unsigned short Bs[3 * 128 * 64];
    const int m0 = blockIdx.x * 256;
    const int n0 = blockIdx.y * 128;

    f32x4 acc[4][4];
    gemm256_mainloop(ctx, Wob, m0, n0, As, Bs, acc);

    const int lane = threadIdx.x & 63, w = threadIdx.x >> 6;
    const int wr = w >> 1, wc = w & 1;
    const int lg = lane >> 4, ll = lane & 15;
#pragma unroll
    for (int i = 0; i < 4; i++)
#pragma unroll
        for (int j = 0; j < 4; j++) {
            int col = n0 + wc * 64 + j * 16 + ll;
            float bias = bo[col];
#pragma unroll
            for (int r = 0; r < 4; r++) {
                int row = m0 + wr * 64 + i * 16 + lg * 4 + r;
                out[(size_t)row * DMODEL + col] = acc[i][j][r] + bias;
            }
        }
}

// ---------------- flash attention (causal), Q-tile 128, KV-tile 64, 4 waves ----------------
// S^T structure: st = mfma(K, Q) so q = lane&15 (lane-local rows), k = cb*16+4*lg+r.
// Softmax in-register + 2 shfl. P packed via v_cvt_pk_bf16_f32, b64 LDS writes.
// PV computed as O^T = mfma(Vt-frag, P-frag). Raw s_barrier pipeline (T4).
__global__ __launch_bounds__(256) void attn(const unsigned short* __restrict__ Qg,
                                            const unsigned short* __restrict__ Kg,
                                            const unsigned short* __restrict__ Vg,
                                            unsigned short* __restrict__ ctx) {
    __shared__ __attribute__((aligned(16))) unsigned short Ks[64][72];
    __shared__ __attribute__((aligned(16))) unsigned short Vs[64][72];
    __shared__ __attribute__((aligned(16))) unsigned short Pl[128][76];

    const int tid = threadIdx.x, lane = tid & 63, w = tid >> 6;
    const int wq = w * 32;
    const int lg = lane >> 4;
    const int ll = lane & 15;
    const int bh = blockIdx.x;
    const int q0 = (gridDim.y - 1 - blockIdx.y) * 128;   // heavy tiles first (LPT)
    const unsigned short* Qh = Qg + (size_t)bh * TSEQ * HD;
    const unsigned short* Kh = Kg + (size_t)bh * TSEQ * HD;
    const unsigned short* Vh = Vg + (size_t)bh * HD * TSEQ;

    short8 qf[2][2];
#pragma unroll
    for (int rb = 0; rb < 2; rb++)
#pragma unroll
        for (int ks = 0; ks < 2; ks++)
            qf[rb][ks] = *(const short8*)(Qh + (size_t)(q0 + wq + rb * 16 + ll) * HD + ks * 32 + lg * 8);

    float mrun[2] = {-1e30f, -1e30f}, lrun[2] = {0.f, 0.f};
    const f32x4 zerov = {0.f, 0.f, 0.f, 0.f};
    f32x4 o_t[2][4];
#pragma unroll
    for (int rb = 0; rb < 2; rb++)
#pragma unroll
        for (int db = 0; db < 4; db++) o_t[rb][db] = zerov;

    const int sr = tid >> 3;
    const int sc = (tid & 7) * 8;
    short8 kreg0, kreg1, vreg0, vreg1;
    {
        kreg0 = *(const short8*)(Kh + (size_t)(sr) * HD + sc);
        kreg1 = *(const short8*)(Kh + (size_t)(sr + 32) * HD + sc);
        vreg0 = *(const short8*)(Vh + (size_t)sr * TSEQ + sc);
        vreg1 = *(const short8*)(Vh + (size_t)(sr + 32) * TSEQ + sc);
    }

    const int nkv = q0 / 64 + 2;
    for (int kt = 0; kt < nkv; kt++) {
        const int kv0 = kt * 64;
        __builtin_amdgcn_s_barrier();
        __builtin_amdgcn_sched_barrier(0);
        *(short8*)&Ks[sr][sc] = kreg0;
        *(short8*)&Ks[sr + 32][sc] = kreg1;
        *(short8*)&Vs[sr][sc] = vreg0;
        *(short8*)&Vs[sr + 32][sc] = vreg1;
        if (kt + 1 < nkv) {
            const int nv0 = kv0 + 64;
            kreg0 = *(const short8*)(Kh + (size_t)(nv0 + sr) * HD + sc);
            kreg1 = *(const short8*)(Kh + (size_t)(nv0 + sr + 32) * HD + sc);
            vreg0 = *(const short8*)(Vh + (size_t)sr * TSEQ + nv0 + sc);
            vreg1 = *(const short8*)(Vh + (size_t)(sr + 32) * TSEQ + nv0 + sc);
        }
        __builtin_amdgcn_sched_barrier(0);
        asm volatile("s_waitcnt lgkmcnt(0)" ::: "memory");
        __builtin_amdgcn_s_barrier();
        __builtin_amdgcn_sched_barrier(0);

        short8 af0[4], af1[4];
#pragma unroll
        for (int cb = 0; cb < 4; cb++) {
            af0[cb] = *(const short8*)&Ks[cb * 16 + ll][lg * 8];
            af1[cb] = *(const short8*)&Ks[cb * 16 + ll][32 + lg * 8];
        }
        f32x4 st[2][4];
#pragma unroll
        for (int rb = 0; rb < 2; rb++)
#pragma unroll
            for (int cb = 0; cb < 4; cb++)
                st[rb][cb] = __builtin_amdgcn_mfma_f32_16x16x32_bf16(af0[cb], qf[rb][0], zerov, 0, 0, 0);
#pragma unroll
        for (int rb = 0; rb < 2; rb++)
#pragma unroll
            for (int cb = 0; cb < 4; cb++)
                st[rb][cb] = __builtin_amdgcn_mfma_f32_16x16x32_bf16(af1[cb], qf[rb][1], st[rb][cb], 0, 0, 0);

        if (kv0 + 63 > q0) {
#pragma unroll
            for (int rb = 0; rb < 2; rb++)
#pragma unroll
                for (int cb = 0; cb < 4; cb++)
#pragma unroll
                    for (int r = 0; r < 4; r++) {
                        int kvl = cb * 16 + lg * 4 + r;
                        int ql = wq + rb * 16 + ll;
                        if (kv0 + kvl > q0 + ql) st[rb][cb][r] = -1e30f;
                    }
        }

        float mx[2];
#pragma unroll
        for (int rb = 0; rb < 2; rb++) {
            float a0 = fmaxf(fmaxf(st[rb][0][0], st[rb][0][1]), fmaxf(st[rb][0][2], st[rb][0][3]));
            float a1 = fmaxf(fmaxf(st[rb][1][0], st[rb][1][1]), fmaxf(st[rb][1][2], st[rb][1][3]));
            float a2 = fmaxf(fmaxf(st[rb][2][0], st[rb][2][1]), fmaxf(st[rb][2][2], st[rb][2][3]));
            float a3 = fmaxf(fmaxf(st[rb][3][0], st[rb][3][1]), fmaxf(st[rb][3][2], st[rb][3][3]));
            float m = fmaxf(fmaxf(a0, a1), fmaxf(a2, a3));
            m = fmaxf(m, __shfl_xor(m, 16));
            m = fmaxf(m, __shfl_xor(m, 32));
            mx[rb] = m;
        }
        float need = fmaxf(mx[0] - mrun[0], mx[1] - mrun[1]);
        if (__any(need > 8.f)) {
#pragma unroll
            for (int rb = 0; rb < 2; rb++) {
                float mold = mrun[rb];
                float mn = fmaxf(mold, mx[rb]);
                float rs = __builtin_amdgcn_exp2f(mold - mn);
                mrun[rb] = mn;
                lrun[rb] *= rs;
#pragma unroll
                for (int db = 0; db < 4; db++)
#pragma unroll
                    for (int r = 0; r < 4; r++) o_t[rb][db][r] *= rs;
            }
        }
#pragma unroll
        for (int rb = 0; rb < 2; rb++) {
            float sum = 0.f;
#pragma unroll
            for (int cb = 0; cb < 4; cb++) {
                float p0 = __builtin_amdgcn_exp2f(st[rb][cb][0] - mrun[rb]);
                float p1 = __builtin_amdgcn_exp2f(st[rb][cb][1] - mrun[rb]);
                float p2 = __builtin_amdgcn_exp2f(st[rb][cb][2] - mrun[rb]);
                float p3 = __builtin_amdgcn_exp2f(st[rb][cb][3] - mrun[rb]);
                sum += (p0 + p1) + (p2 + p3);
                uint2 pw;
                pw.x = cvtpk(p0, p1);
                pw.y = cvtpk(p2, p3);
                *(uint2*)&Pl[wq + rb * 16 + ll][cb * 16 + lg * 4] = pw;
            }
            sum += __shfl_xor(sum, 16);
            sum += __shfl_xor(sum, 32);
            lrun[rb] += sum;
        }
        asm volatile("s_waitcnt lgkmcnt(0)" ::: "memory");
        __builtin_amdgcn_sched_barrier(0);

#pragma unroll
        for (int ks = 0; ks < 2; ks++) {
            short8 pa[2], va[4];
#pragma unroll
            for (int rb = 0; rb < 2; rb++)
                pa[rb] = *(const short8*)&Pl[wq + rb * 16 + ll][ks * 32 + lg * 8];
#pragma unroll
            for (int db = 0; db < 4; db++)
                va[db] = *(const short8*)&Vs[db * 16 + ll][ks * 32 + lg * 8];
#pragma unroll
            for (int rb = 0; rb < 2; rb++)
#pragma unroll
                for (int db = 0; db < 4; db++)
                    o_t[rb][db] = __builtin_amdgcn_mfma_f32_16x16x32_bf16(va[db], pa[rb], o_t[rb][db], 0, 0, 0);
        }
    }

    const int b = bh >> 4, h = bh & 15;
#pragma unroll
    for (int rb = 0; rb < 2; rb++) {
        float linv = 1.f / lrun[rb];
#pragma unroll
        for (int db = 0; db < 4; db++) {
            uint2 pw;
            pw.x = cvtpk(o_t[rb][db][0] * linv, o_t[rb][db][1] * linv);
            pw.y = cvtpk(o_t[rb][db][2] * linv, o_t[rb][db][3] * linv);
            *(uint2*)&Pl[wq + rb * 16 + ll][db * 16 + lg * 4] = pw;
        }
    }
    asm volatile("s_waitcnt lgkmcnt(0)" ::: "memory");
    __builtin_amdgcn_sched_barrier(0);
#pragma unroll
    for (int rb = 0; rb < 2; rb++)
#pragma unroll
        for (int half = 0; half < 2; half++) {
            short8 v = *(const short8*)&Pl[wq + rb * 16 + ll][half * 32 + lg * 8];
            size_t row = (size_t)(b * TSEQ + q0 + wq + rb * 16 + ll);
            *(short8*)(ctx + (row * NH + h) * HD + half * 32 + lg * 8) = v;
        }
}

extern "C" void kernel_launch(void* const* d_in, const int* in_sizes, int n_in,
                              void* d_out, int out_size, void* d_ws, size_t ws_size,
                              hipStream_t stream) {
    const float* x  = (const float*)d_in[0];
    const float* Wq = (const float*)d_in[1];
    const float* Wk = (const float*)d_in[2];
    const float* Wv = (const float*)d_in[3];
    const float* Wo = (const float*)d_in[4];
    const float* bo = (const float*)d_in[5];
    float* out = (float*)d_out;

    char* ws = (char*)d_ws;
    unsigned short* xb   = (unsigned short*)(ws);             // 16,777,216 B
    unsigned short* Wqb  = (unsigned short*)(ws + 16777216);
    unsigned short* Wkb  = (unsigned short*)(ws + 18874368);
    unsigned short* Wvb  = (unsigned short*)(ws + 20971520);
    unsigned short* Wob  = (unsigned short*)(ws + 23068672);
    unsigned short* Qb   = (unsigned short*)(ws + 25165824);  // [B,H,T,hd] bf16 (pre-scaled)
    unsigned short* Kb   = (unsigned short*)(ws + 41943040);  // [B,H,T,hd]
    unsigned short* Vtb  = (unsigned short*)(ws + 58720256);  // [B,H,hd,T]
    unsigned short* ctxb = (unsigned short*)(ws + 75497472);  // [B,T,H,hd]

    cast_f32_bf16<<<8192, 256, 0, stream>>>(x, xb, 2097152);
    cast_weights<<<4096, 256, 0, stream>>>(Wq, Wk, Wv, Wo, Wqb, Wkb, Wvb, Wob);

    gemm_qkv<<<dim3(32, 8, 3), 512, 0, stream>>>(xb, Wqb, Wkb, Wvb, Qb, Kb, Vtb);
    attn<<<dim3(64, 16), 256, 0, stream>>>(Qb, Kb, Vtb, ctxb);
    gemm_out<<<dim3(32, 8), 512, 0, stream>>>(ctxb, Wob, bo, out);
}

// Round 9
// 198.346 us; speedup vs baseline: 1.0474x; 1.0084x over previous
//
#include <hip/hip_runtime.h>

#define NH 16
#define HD 64
#define TSEQ 2048
#define DMODEL 1024

typedef __attribute__((ext_vector_type(8))) short short8;
typedef __attribute__((ext_vector_type(4))) float f32x4;

static __device__ __forceinline__ unsigned short f2bf(float f) {
    unsigned u = __builtin_bit_cast(unsigned, f);
    u += 0x7FFF + ((u >> 16) & 1);
    return (unsigned short)(u >> 16);
}

// packed f32x2 -> bf16x2 (low = a, high = b), single VALU op
static __device__ __forceinline__ unsigned cvtpk(float a, float b) {
    unsigned r;
    asm("v_cvt_pk_bf16_f32 %0, %1, %2" : "=v"(r) : "v"(a), "v"(b));
    return r;
}

// ---------------- cast f32 -> bf16 (vectorized) ----------------
__global__ __launch_bounds__(256) void cast_f32_bf16(const float* __restrict__ src,
                                                     unsigned short* __restrict__ dst, int n4) {
    int i = blockIdx.x * 256 + threadIdx.x;
    if (i >= n4) return;
    float4 v = reinterpret_cast<const float4*>(src)[i];
    ushort4 o;
    o.x = f2bf(v.x); o.y = f2bf(v.y); o.z = f2bf(v.z); o.w = f2bf(v.w);
    reinterpret_cast<ushort4*>(dst)[i] = o;
}

__global__ __launch_bounds__(256) void cast_weights(const float* __restrict__ Wq,
                                                    const float* __restrict__ Wk,
                                                    const float* __restrict__ Wv,
                                                    const float* __restrict__ Wo,
                                                    unsigned short* __restrict__ dq,
                                                    unsigned short* __restrict__ dk,
                                                    unsigned short* __restrict__ dv,
                                                    unsigned short* __restrict__ dwo) {
    int g = blockIdx.x >> 10;
    int i = (blockIdx.x & 1023) * 256 + threadIdx.x;
    const float* s = (g == 0) ? Wq : (g == 1) ? Wk : (g == 2) ? Wv : Wo;
    unsigned short* d = (g == 0) ? dq : (g == 1) ? dk : (g == 2) ? dv : dwo;
    float4 v = reinterpret_cast<const float4*>(s)[i];
    ushort4 o;
    o.x = f2bf(v.x); o.y = f2bf(v.y); o.z = f2bf(v.z); o.w = f2bf(v.w);
    reinterpret_cast<ushort4*>(d)[i] = o;
}

// ============ 256x128 GEMM mainloop: 3-deep ring, deep prefetch ============
// C[256x128] = A[M][1024] * Bt[N][1024]^T, bf16 in, f32 acc.
// 512 threads = 8 waves (4M x 2N), per-wave output 64x64 (acc 4x4).
// LDS: A 3-ring [256][64] (96KB) + B 3-ring [128][64] (48KB) = 144KB.
// At K-tile kt: stage kt+2 (consumed ~1200 cyc later -> HBM latency fully
// hidden); ONE vmcnt(6) per K-tile (the 6 just-issued loads stay in flight,
// waits only for kt+1's long-issued data); ONE barrier per K-tile (each
// wave's lgkmcnt(0) precedes its MFMAs which precede the barrier, so the
// mod-3 buffer reuse cannot race). Full-strength XOR swizzle (r8: proven
// zero conflicts): linear gload dest + source col ^ ((row&7)<<3) + same
// XOR on ds_read. setprio(1) around the 32-MFMA cluster.
static __device__ __forceinline__ void gemm256_mainloop(
    const unsigned short* __restrict__ A, const unsigned short* __restrict__ Bt,
    int m0, int n0, unsigned short* As, unsigned short* Bs, f32x4 acc[4][4]) {
    const int tid = threadIdx.x, lane = tid & 63, w = tid >> 6;
    const int wr = w >> 1, wc = w & 1;
    const int lg = lane >> 4, ll = lane & 15;
    const int strow = tid >> 3;                             // 0..63
    const int csw = ((tid & 7) * 8) ^ ((strow & 7) << 3);   // pre-swizzled source col
    const int axor = (ll & 7) << 3;                         // read-side XOR

    const f32x4 zero = {0.f, 0.f, 0.f, 0.f};
#pragma unroll
    for (int i = 0; i < 4; i++)
#pragma unroll
        for (int j = 0; j < 4; j++) acc[i][j] = zero;

    auto stageA = [&](int kt, int buf) {    // 4 loads: A rows 0..255
#pragma unroll
        for (int s = 0; s < 4; ++s) {
            int row = s * 64 + strow;
            __builtin_amdgcn_global_load_lds(
                (const __attribute__((address_space(1))) void*)(A + (size_t)(m0 + row) * DMODEL + kt * 64 + csw),
                (__attribute__((address_space(3))) void*)(As + buf * 16384 + s * 4096 + w * 512), 16, 0, 0);
        }
    };
    auto stageB = [&](int kt, int buf) {    // 2 loads: B rows 0..127
#pragma unroll
        for (int s = 0; s < 2; ++s) {
            int row = s * 64 + strow;
            __builtin_amdgcn_global_load_lds(
                (const __attribute__((address_space(1))) void*)(Bt + (size_t)(n0 + row) * DMODEL + kt * 64 + csw),
                (__attribute__((address_space(3))) void*)(Bs + buf * 8192 + s * 4096 + w * 512), 16, 0, 0);
        }
    };

    // prologue: tiles 0 and 1 staged; full drain once
    stageA(0, 0); stageB(0, 0);
    stageA(1, 1); stageB(1, 1);
    asm volatile("s_waitcnt vmcnt(0)" ::: "memory");
    __builtin_amdgcn_s_barrier();
    __builtin_amdgcn_sched_barrier(0);

    int pb = 0;   // kt % 3
#pragma unroll 1
    for (int kt = 0; kt < 16; ++kt) {
        // 16 ds_reads from buf[pb] (both K-halves)
        short8 af[2][4], bf[2][4];
#pragma unroll
        for (int ks = 0; ks < 2; ks++) {
#pragma unroll
            for (int i = 0; i < 4; i++)
                af[ks][i] = *(const short8*)(As + pb * 16384 + (wr * 64 + i * 16 + ll) * 64 + ((ks * 32 + lg * 8) ^ axor));
#pragma unroll
            for (int j = 0; j < 4; j++)
                bf[ks][j] = *(const short8*)(Bs + pb * 8192 + (wc * 64 + j * 16 + ll) * 64 + ((ks * 32 + lg * 8) ^ axor));
        }
        // stage kt+2 into the ring slot just freed (read at kt-1)
        const int pn = (pb + 2 >= 3) ? (pb - 1) : (pb + 2);
        if (kt + 2 < 16) { stageA(kt + 2, pn); stageB(kt + 2, pn); }

        asm volatile("s_waitcnt lgkmcnt(0)" ::: "memory");
        __builtin_amdgcn_sched_barrier(0);
        __builtin_amdgcn_s_setprio(1);
#pragma unroll
        for (int ks = 0; ks < 2; ks++)
#pragma unroll
            for (int i = 0; i < 4; i++)
#pragma unroll
                for (int j = 0; j < 4; j++)
                    acc[i][j] = __builtin_amdgcn_mfma_f32_16x16x32_bf16(af[ks][i], bf[ks][j], acc[i][j], 0, 0, 0);
        __builtin_amdgcn_s_setprio(0);
        __builtin_amdgcn_sched_barrier(0);
        // counted wait: kt+2's 6 loads stay in flight; ensures kt+1 landed
        if (kt + 2 < 16) {
            asm volatile("s_waitcnt vmcnt(6)" ::: "memory");
        } else {
            asm volatile("s_waitcnt vmcnt(0)" ::: "memory");
        }
        __builtin_amdgcn_s_barrier();
        __builtin_amdgcn_sched_barrier(0);
        pb = (pb + 1 >= 3) ? 0 : (pb + 1);
    }
}

// ---------------- QKV projection ----------------
#define QSCALE 0.180336880f
__global__ __launch_bounds__(512) void gemm_qkv(const unsigned short* __restrict__ xb,
                                                const unsigned short* __restrict__ Wqb,
                                                const unsigned short* __restrict__ Wkb,
                                                const unsigned short* __restrict__ Wvb,
                                                unsigned short* __restrict__ Q,
                                                unsigned short* __restrict__ K,
                                                unsigned short* __restrict__ Vt) {
    __shared__ __attribute__((aligned(16))) unsigned short As[3 * 256 * 64];
    __shared__ __attribute__((aligned(16))) unsigned short Bs[3 * 128 * 64];
    const int m0 = blockIdx.x * 256;
    const int n0 = blockIdx.y * 128;
    const int z = blockIdx.z;
    const unsigned short* Bt = (z == 0) ? Wqb : ((z == 1) ? Wkb : Wvb);
    unsigned short* out = (z == 0) ? Q : ((z == 1) ? K : Vt);

    f32x4 acc[4][4];
    gemm256_mainloop(xb, Bt, m0, n0, As, Bs, acc);

    const int lane = threadIdx.x & 63, w = threadIdx.x >> 6;
    const int wr = w >> 1, wc = w & 1;
    const int lg = lane >> 4, ll = lane & 15;
    const float sc = (z == 0) ? QSCALE : 1.0f;
#pragma unroll
    for (int i = 0; i < 4; i++)
#pragma unroll
        for (int j = 0; j < 4; j++)
#pragma unroll
            for (int r = 0; r < 4; r++) {
                int row = m0 + wr * 64 + i * 16 + lg * 4 + r;   // b*2048 + t
                int col = n0 + wc * 64 + j * 16 + ll;           // h*64 + d
                int b = row >> 11, t = row & 2047;
                int h = col >> 6, d = col & 63;
                unsigned short v = f2bf(acc[i][j][r] * sc);
                if (z == 2)
                    out[(((size_t)(b * NH + h)) * HD + d) * TSEQ + t] = v;
                else
                    out[(((size_t)(b * NH + h)) * TSEQ + t) * HD + d] = v;
            }
}

// ---------------- output projection ----------------
__global__ __launch_bounds__(512) void gemm_out(const unsigned short* __restrict__ ctx,
                                                const unsigned short* __restrict__ Wob,
                                                const float* __restrict__ bo,
                                                float* __restrict__ out) {
    __shared__ __attribute__((aligned(16))) unsigned short As[3 * 256 * 64];
    __shared__ __attribute__((aligned(16))) unsigned short Bs[3 * 128 * 64];
    const int m0 = blockIdx.x * 256;
    const int n0 = blockIdx.y * 128;

    f32x4 acc[4][4];
    gemm256_mainloop(ctx, Wob, m0, n0, As, Bs, acc);

    const int lane = threadIdx.x & 63, w = threadIdx.x >> 6;
    const int wr = w >> 1, wc = w & 1;
    const int lg = lane >> 4, ll = lane & 15;
#pragma unroll
    for (int i = 0; i < 4; i++)
#pragma unroll
        for (int j = 0; j < 4; j++) {
            int col = n0 + wc * 64 + j * 16 + ll;
            float bias = bo[col];
#pragma unroll
            for (int r = 0; r < 4; r++) {
                int row = m0 + wr * 64 + i * 16 + lg * 4 + r;
                out[(size_t)row * DMODEL + col] = acc[i][j][r] + bias;
            }
        }
}

// ---------------- flash attention (causal), Q-tile 128, KV-tile 64, 4 waves ----------------
// S^T structure: st = mfma(K, Q) so q = lane&15 (lane-local rows), k = cb*16+4*lg+r.
// Softmax in-register + 2 shfl. P packed via v_cvt_pk_bf16_f32, b64 LDS writes.
// PV computed as O^T = mfma(Vt-frag, P-frag). Raw s_barrier pipeline (T4).
__global__ __launch_bounds__(256) void attn(const unsigned short* __restrict__ Qg,
                                            const unsigned short* __restrict__ Kg,
                                            const unsigned short* __restrict__ Vg,
                                            unsigned short* __restrict__ ctx) {
    __shared__ __attribute__((aligned(16))) unsigned short Ks[64][72];
    __shared__ __attribute__((aligned(16))) unsigned short Vs[64][72];
    __shared__ __attribute__((aligned(16))) unsigned short Pl[128][76];

    const int tid = threadIdx.x, lane = tid & 63, w = tid >> 6;
    const int wq = w * 32;
    const int lg = lane >> 4;
    const int ll = lane & 15;
    const int bh = blockIdx.x;
    const int q0 = (gridDim.y - 1 - blockIdx.y) * 128;   // heavy tiles first (LPT)
    const unsigned short* Qh = Qg + (size_t)bh * TSEQ * HD;
    const unsigned short* Kh = Kg + (size_t)bh * TSEQ * HD;
    const unsigned short* Vh = Vg + (size_t)bh * HD * TSEQ;

    short8 qf[2][2];
#pragma unroll
    for (int rb = 0; rb < 2; rb++)
#pragma unroll
        for (int ks = 0; ks < 2; ks++)
            qf[rb][ks] = *(const short8*)(Qh + (size_t)(q0 + wq + rb * 16 + ll) * HD + ks * 32 + lg * 8);

    float mrun[2] = {-1e30f, -1e30f}, lrun[2] = {0.f, 0.f};
    const f32x4 zerov = {0.f, 0.f, 0.f, 0.f};
    f32x4 o_t[2][4];
#pragma unroll
    for (int rb = 0; rb < 2; rb++)
#pragma unroll
        for (int db = 0; db < 4; db++) o_t[rb][db] = zerov;

    const int sr = tid >> 3;
    const int sc = (tid & 7) * 8;
    short8 kreg0, kreg1, vreg0, vreg1;
    {
        kreg0 = *(const short8*)(Kh + (size_t)(sr) * HD + sc);
        kreg1 = *(const short8*)(Kh + (size_t)(sr + 32) * HD + sc);
        vreg0 = *(const short8*)(Vh + (size_t)sr * TSEQ + sc);
        vreg1 = *(const short8*)(Vh + (size_t)(sr + 32) * TSEQ + sc);
    }

    const int nkv = q0 / 64 + 2;
    for (int kt = 0; kt < nkv; kt++) {
        const int kv0 = kt * 64;
        __builtin_amdgcn_s_barrier();
        __builtin_amdgcn_sched_barrier(0);
        *(short8*)&Ks[sr][sc] = kreg0;
        *(short8*)&Ks[sr + 32][sc] = kreg1;
        *(short8*)&Vs[sr][sc] = vreg0;
        *(short8*)&Vs[sr + 32][sc] = vreg1;
        if (kt + 1 < nkv) {
            const int nv0 = kv0 + 64;
            kreg0 = *(const short8*)(Kh + (size_t)(nv0 + sr) * HD + sc);
            kreg1 = *(const short8*)(Kh + (size_t)(nv0 + sr + 32) * HD + sc);
            vreg0 = *(const short8*)(Vh + (size_t)sr * TSEQ + nv0 + sc);
            vreg1 = *(const short8*)(Vh + (size_t)(sr + 32) * TSEQ + nv0 + sc);
        }
        __builtin_amdgcn_sched_barrier(0);
        asm volatile("s_waitcnt lgkmcnt(0)" ::: "memory");
        __builtin_amdgcn_s_barrier();
        __builtin_amdgcn_sched_barrier(0);

        short8 af0[4], af1[4];
#pragma unroll
        for (int cb = 0; cb < 4; cb++) {
            af0[cb] = *(const short8*)&Ks[cb * 16 + ll][lg * 8];
            af1[cb] = *(const short8*)&Ks[cb * 16 + ll][32 + lg * 8];
        }
        f32x4 st[2][4];
#pragma unroll
        for (int rb = 0; rb < 2; rb++)
#pragma unroll
            for (int cb = 0; cb < 4; cb++)
                st[rb][cb] = __builtin_amdgcn_mfma_f32_16x16x32_bf16(af0[cb], qf[rb][0], zerov, 0, 0, 0);
#pragma unroll
        for (int rb = 0; rb < 2; rb++)
#pragma unroll
            for (int cb = 0; cb < 4; cb++)
                st[rb][cb] = __builtin_amdgcn_mfma_f32_16x16x32_bf16(af1[cb], qf[rb][1], st[rb][cb], 0, 0, 0);

        if (kv0 + 63 > q0) {
#pragma unroll
            for (int rb = 0; rb < 2; rb++)
#pragma unroll
                for (int cb = 0; cb < 4; cb++)
#pragma unroll
                    for (int r = 0; r < 4; r++) {
                        int kvl = cb * 16 + lg * 4 + r;
                        int ql = wq + rb * 16 + ll;
                        if (kv0 + kvl > q0 + ql) st[rb][cb][r] = -1e30f;
                    }
        }

        float mx[2];
#pragma unroll
        for (int rb = 0; rb < 2; rb++) {
            float a0 = fmaxf(fmaxf(st[rb][0][0], st[rb][0][1]), fmaxf(st[rb][0][2], st[rb][0][3]));
            float a1 = fmaxf(fmaxf(st[rb][1][0], st[rb][1][1]), fmaxf(st[rb][1][2], st[rb][1][3]));
            float a2 = fmaxf(fmaxf(st[rb][2][0], st[rb][2][1]), fmaxf(st[rb][2][2], st[rb][2][3]));
            float a3 = fmaxf(fmaxf(st[rb][3][0], st[rb][3][1]), fmaxf(st[rb][3][2], st[rb][3][3]));
            float m = fmaxf(fmaxf(a0, a1), fmaxf(a2, a3));
            m = fmaxf(m, __shfl_xor(m, 16));
            m = fmaxf(m, __shfl_xor(m, 32));
            mx[rb] = m;
        }
        float need = fmaxf(mx[0] - mrun[0], mx[1] - mrun[1]);
        if (__any(need > 8.f)) {
#pragma unroll
            for (int rb = 0; rb < 2; rb++) {
                float mold = mrun[rb];
                float mn = fmaxf(mold, mx[rb]);
                float rs = __builtin_amdgcn_exp2f(mold - mn);
                mrun[rb] = mn;
                lrun[rb] *= rs;
#pragma unroll
                for (int db = 0; db < 4; db++)
#pragma unroll
                    for (int r = 0; r < 4; r++) o_t[rb][db][r] *= rs;
            }
        }
#pragma unroll
        for (int rb = 0; rb < 2; rb++) {
            float sum = 0.f;
#pragma unroll
            for (int cb = 0; cb < 4; cb++) {
                float p0 = __builtin_amdgcn_exp2f(st[rb][cb][0] - mrun[rb]);
                float p1 = __builtin_amdgcn_exp2f(st[rb][cb][1] - mrun[rb]);
                float p2 = __builtin_amdgcn_exp2f(st[rb][cb][2] - mrun[rb]);
                float p3 = __builtin_amdgcn_exp2f(st[rb][cb][3] - mrun[rb]);
                sum += (p0 + p1) + (p2 + p3);
                uint2 pw;
                pw.x = cvtpk(p0, p1);
                pw.y = cvtpk(p2, p3);
                *(uint2*)&Pl[wq + rb * 16 + ll][cb * 16 + lg * 4] = pw;
            }
            sum += __shfl_xor(sum, 16);
            sum += __shfl_xor(sum, 32);
            lrun[rb] += sum;
        }
        asm volatile("s_waitcnt lgkmcnt(0)" ::: "memory");
        __builtin_amdgcn_sched_barrier(0);

#pragma unroll
        for (int ks = 0; ks < 2; ks++) {
            short8 pa[2], va[4];
#pragma unroll
            for (int rb = 0; rb < 2; rb++)
                pa[rb] = *(const short8*)&Pl[wq + rb * 16 + ll][ks * 32 + lg * 8];
#pragma unroll
            for (int db = 0; db < 4; db++)
                va[db] = *(const short8*)&Vs[db * 16 + ll][ks * 32 + lg * 8];
#pragma unroll
            for (int rb = 0; rb < 2; rb++)
#pragma unroll
                for (int db = 0; db < 4; db++)
                    o_t[rb][db] = __builtin_amdgcn_mfma_f32_16x16x32_bf16(va[db], pa[rb], o_t[rb][db], 0, 0, 0);
        }
    }

    const int b = bh >> 4, h = bh & 15;
#pragma unroll
    for (int rb = 0; rb < 2; rb++) {
        float linv = 1.f / lrun[rb];
#pragma unroll
        for (int db = 0; db < 4; db++) {
            uint2 pw;
            pw.x = cvtpk(o_t[rb][db][0] * linv, o_t[rb][db][1] * linv);
            pw.y = cvtpk(o_t[rb][db][2] * linv, o_t[rb][db][3] * linv);
            *(uint2*)&Pl[wq + rb * 16 + ll][db * 16 + lg * 4] = pw;
        }
    }
    asm volatile("s_waitcnt lgkmcnt(0)" ::: "memory");
    __builtin_amdgcn_sched_barrier(0);
#pragma unroll
    for (int rb = 0; rb < 2; rb++)
#pragma unroll
        for (int half = 0; half < 2; half++) {
            short8 v = *(const short8*)&Pl[wq + rb * 16 + ll][half * 32 + lg * 8];
            size_t row = (size_t)(b * TSEQ + q0 + wq + rb * 16 + ll);
            *(short8*)(ctx + (row * NH + h) * HD + half * 32 + lg * 8) = v;
        }
}

extern "C" void kernel_launch(void* const* d_in, const int* in_sizes, int n_in,
                              void* d_out, int out_size, void* d_ws, size_t ws_size,
                              hipStream_t stream) {
    const float* x  = (const float*)d_in[0];
    const float* Wq = (const float*)d_in[1];
    const float* Wk = (const float*)d_in[2];
    const float* Wv = (const float*)d_in[3];
    const float* Wo = (const float*)d_in[4];
    const float* bo = (const float*)d_in[5];
    float* out = (float*)d_out;

    char* ws = (char*)d_ws;
    unsigned short* xb   = (unsigned short*)(ws);             // 16,777,216 B
    unsigned short* Wqb  = (unsigned short*)(ws + 16777216);
    unsigned short* Wkb  = (unsigned short*)(ws + 18874368);
    unsigned short* Wvb  = (unsigned short*)(ws + 20971520);
    unsigned short* Wob  = (unsigned short*)(ws + 23068672);
    unsigned short* Qb   = (unsigned short*)(ws + 25165824);  // [B,H,T,hd] bf16 (pre-scaled)
    unsigned short* Kb   = (unsigned short*)(ws + 41943040);  // [B,H,T,hd]
    unsigned short* Vtb  = (unsigned short*)(ws + 58720256);  // [B,H,hd,T]
    unsigned short* ctxb = (unsigned short*)(ws + 75497472);  // [B,T,H,hd]

    cast_f32_bf16<<<8192, 256, 0, stream>>>(x, xb, 2097152);
    cast_weights<<<4096, 256, 0, stream>>>(Wq, Wk, Wv, Wo, Wqb, Wkb, Wvb, Wob);

    gemm_qkv<<<dim3(32, 8, 3), 512, 0, stream>>>(xb, Wqb, Wkb, Wvb, Qb, Kb, Vtb);
    attn<<<dim3(64, 16), 256, 0, stream>>>(Qb, Kb, Vtb, ctxb);
    gemm_out<<<dim3(32, 8), 512, 0, stream>>>(ctxb, Wob, bo, out);
}

// Round 10
// 183.766 us; speedup vs baseline: 1.1305x; 1.0793x over previous
//
#include <hip/hip_runtime.h>

#define NH 16
#define HD 64
#define TSEQ 2048
#define DMODEL 1024

typedef __attribute__((ext_vector_type(8))) short short8;
typedef __attribute__((ext_vector_type(4))) float f32x4;

static __device__ __forceinline__ unsigned short f2bf(float f) {
    unsigned u = __builtin_bit_cast(unsigned, f);
    u += 0x7FFF + ((u >> 16) & 1);
    return (unsigned short)(u >> 16);
}

// packed f32x2 -> bf16x2 (low = a, high = b), single VALU op
static __device__ __forceinline__ unsigned cvtpk(float a, float b) {
    unsigned r;
    asm("v_cvt_pk_bf16_f32 %0, %1, %2" : "=v"(r) : "v"(a), "v"(b));
    return r;
}

// ---------------- cast f32 -> bf16 (vectorized) ----------------
__global__ __launch_bounds__(256) void cast_f32_bf16(const float* __restrict__ src,
                                                     unsigned short* __restrict__ dst, int n4) {
    int i = blockIdx.x * 256 + threadIdx.x;
    if (i >= n4) return;
    float4 v = reinterpret_cast<const float4*>(src)[i];
    ushort4 o;
    o.x = f2bf(v.x); o.y = f2bf(v.y); o.z = f2bf(v.z); o.w = f2bf(v.w);
    reinterpret_cast<ushort4*>(dst)[i] = o;
}

__global__ __launch_bounds__(256) void cast_weights(const float* __restrict__ Wq,
                                                    const float* __restrict__ Wk,
                                                    const float* __restrict__ Wv,
                                                    const float* __restrict__ Wo,
                                                    unsigned short* __restrict__ dq,
                                                    unsigned short* __restrict__ dk,
                                                    unsigned short* __restrict__ dv,
                                                    unsigned short* __restrict__ dwo) {
    int g = blockIdx.x >> 10;
    int i = (blockIdx.x & 1023) * 256 + threadIdx.x;
    const float* s = (g == 0) ? Wq : (g == 1) ? Wk : (g == 2) ? Wv : Wo;
    unsigned short* d = (g == 0) ? dq : (g == 1) ? dk : (g == 2) ? dv : dwo;
    float4 v = reinterpret_cast<const float4*>(s)[i];
    ushort4 o;
    o.x = f2bf(v.x); o.y = f2bf(v.y); o.z = f2bf(v.z); o.w = f2bf(v.w);
    reinterpret_cast<ushort4*>(d)[i] = o;
}

// ============ 128x128 GEMM mainloop: BK=32, 3-ring, 3 blocks/CU ============
// C[128x128] = A[M][1024] * Bt[N][1024]^T, bf16 in, f32 acc.
// 256 threads = 4 waves (2M x 2N), per-wave 64x64 (acc 4x4).
// LDS: A 3-ring [128][32] (24KB) + B 3-ring (24KB) = 48KB -> 3 blocks/CU
// (12 waves/CU: inter-block TLP hides the per-block stalls — the r5-r9
// plateau was 1-2 blocks/CU with lockstep waves). At kt stage kt+2
// (~700 cyc cover); ONE barrier + vmcnt(4) per K-tile (kt+2's 4 loads
// stay in flight; kt+1 guaranteed landed). Swizzle: LDS[row][u] holds
// global[row][u^(row&3)] (16B units) — residual 4-way conflict on a
// non-binding DS pipe. Reader XORs identically (rule 21).
static __device__ __forceinline__ void gemm128_mainloop(
    const unsigned short* __restrict__ A, const unsigned short* __restrict__ Bt,
    int m0, int n0, unsigned short* As, unsigned short* Bs, f32x4 acc[4][4]) {
    const int tid = threadIdx.x, lane = tid & 63, w = tid >> 6;
    const int wr = w >> 1, wc = w & 1;
    const int lg = lane >> 4, ll = lane & 15;
    const int strow = tid >> 2;          // 0..63
    const int su = tid & 3;              // 16B unit 0..3
    const int ruxor = (ll & 3);          // read-side XOR (row&3 == ll&3 for frag rows)

    const f32x4 zero = {0.f, 0.f, 0.f, 0.f};
#pragma unroll
    for (int i = 0; i < 4; i++)
#pragma unroll
        for (int j = 0; j < 4; j++) acc[i][j] = zero;

    auto stage = [&](const unsigned short* M, int base, unsigned short* L, int kt, int slot) {
#pragma unroll
        for (int s = 0; s < 2; ++s) {
            int row = s * 64 + strow;
            int gcol = kt * 32 + ((su ^ (row & 3)) * 8);
            __builtin_amdgcn_global_load_lds(
                (const __attribute__((address_space(1))) void*)(M + (size_t)(base + row) * DMODEL + gcol),
                (__attribute__((address_space(3))) void*)(L + slot * 4096 + row * 32 + su * 8), 16, 0, 0);
        }
    };

    // prologue: tiles 0,1; wait tile0 (tile1's 4 loads stay in flight)
    stage(A, m0, As, 0, 0); stage(Bt, n0, Bs, 0, 0);
    stage(A, m0, As, 1, 1); stage(Bt, n0, Bs, 1, 1);
    asm volatile("s_waitcnt vmcnt(4)" ::: "memory");
    __builtin_amdgcn_s_barrier();
    __builtin_amdgcn_sched_barrier(0);

    int pb = 0;
#pragma unroll 1
    for (int kt = 0; kt < 32; ++kt) {
        short8 af[4], bf[4];
#pragma unroll
        for (int i = 0; i < 4; i++)
            af[i] = *(const short8*)(As + pb * 4096 + (wr * 64 + i * 16 + ll) * 32 + ((lg ^ ruxor) * 8));
#pragma unroll
        for (int j = 0; j < 4; j++)
            bf[j] = *(const short8*)(Bs + pb * 4096 + (wc * 64 + j * 16 + ll) * 32 + ((lg ^ ruxor) * 8));
        const int pn = (pb + 2 >= 3) ? (pb - 1) : (pb + 2);
        if (kt + 2 < 32) { stage(A, m0, As, kt + 2, pn); stage(Bt, n0, Bs, kt + 2, pn); }

        asm volatile("s_waitcnt lgkmcnt(0)" ::: "memory");
        __builtin_amdgcn_sched_barrier(0);
        __builtin_amdgcn_s_setprio(1);
#pragma unroll
        for (int i = 0; i < 4; i++)
#pragma unroll
            for (int j = 0; j < 4; j++)
                acc[i][j] = __builtin_amdgcn_mfma_f32_16x16x32_bf16(af[i], bf[j], acc[i][j], 0, 0, 0);
        __builtin_amdgcn_s_setprio(0);
        __builtin_amdgcn_sched_barrier(0);
        if (kt + 2 < 32) {
            asm volatile("s_waitcnt vmcnt(4)" ::: "memory");   // kt+1 landed; kt+2 in flight
        } else {
            asm volatile("s_waitcnt vmcnt(0)" ::: "memory");
        }
        __builtin_amdgcn_s_barrier();
        __builtin_amdgcn_sched_barrier(0);
        pb = (pb + 1 >= 3) ? 0 : (pb + 1);
    }
}

// ---------------- QKV projection ----------------
#define QSCALE 0.180336880f
__global__ __launch_bounds__(256) void gemm_qkv(const unsigned short* __restrict__ xb,
                                                const unsigned short* __restrict__ Wqb,
                                                const unsigned short* __restrict__ Wkb,
                                                const unsigned short* __restrict__ Wvb,
                                                unsigned short* __restrict__ Q,
                                                unsigned short* __restrict__ K,
                                                unsigned short* __restrict__ Vt) {
    __shared__ __attribute__((aligned(16))) unsigned short As[3 * 128 * 32];
    __shared__ __attribute__((aligned(16))) unsigned short Bs[3 * 128 * 32];
    const int m0 = blockIdx.x * 128;
    const int n0 = blockIdx.y * 128;
    const int z = blockIdx.z;
    const unsigned short* Bt = (z == 0) ? Wqb : ((z == 1) ? Wkb : Wvb);
    unsigned short* out = (z == 0) ? Q : ((z == 1) ? K : Vt);

    f32x4 acc[4][4];
    gemm128_mainloop(xb, Bt, m0, n0, As, Bs, acc);

    const int lane = threadIdx.x & 63, w = threadIdx.x >> 6;
    const int wr = w >> 1, wc = w & 1;
    const int lg = lane >> 4, ll = lane & 15;
    const float sc = (z == 0) ? QSCALE : 1.0f;
#pragma unroll
    for (int i = 0; i < 4; i++)
#pragma unroll
        for (int j = 0; j < 4; j++)
#pragma unroll
            for (int r = 0; r < 4; r++) {
                int row = m0 + wr * 64 + i * 16 + lg * 4 + r;   // b*2048 + t
                int col = n0 + wc * 64 + j * 16 + ll;           // h*64 + d
                int b = row >> 11, t = row & 2047;
                int h = col >> 6, d = col & 63;
                unsigned short v = f2bf(acc[i][j][r] * sc);
                if (z == 2)
                    out[(((size_t)(b * NH + h)) * HD + d) * TSEQ + t] = v;
                else
                    out[(((size_t)(b * NH + h)) * TSEQ + t) * HD + d] = v;
            }
}

// ---------------- output projection ----------------
__global__ __launch_bounds__(256) void gemm_out(const unsigned short* __restrict__ ctx,
                                                const unsigned short* __restrict__ Wob,
                                                const float* __restrict__ bo,
                                                float* __restrict__ out) {
    __shared__ __attribute__((aligned(16))) unsigned short As[3 * 128 * 32];
    __shared__ __attribute__((aligned(16))) unsigned short Bs[3 * 128 * 32];
    const int m0 = blockIdx.x * 128;
    const int n0 = blockIdx.y * 128;

    f32x4 acc[4][4];
    gemm128_mainloop(ctx, Wob, m0, n0, As, Bs, acc);

    const int lane = threadIdx.x & 63, w = threadIdx.x >> 6;
    const int wr = w >> 1, wc = w & 1;
    const int lg = lane >> 4, ll = lane & 15;
#pragma unroll
    for (int i = 0; i < 4; i++)
#pragma unroll
        for (int j = 0; j < 4; j++) {
            int col = n0 + wc * 64 + j * 16 + ll;
            float bias = bo[col];
#pragma unroll
            for (int r = 0; r < 4; r++) {
                int row = m0 + wr * 64 + i * 16 + lg * 4 + r;
                out[(size_t)row * DMODEL + col] = acc[i][j][r] + bias;
            }
        }
}

// ---------------- flash attention (causal), Q-tile 256, KV-tile 64, 8 waves ----------------
// S^T structure (r5-proven): per-wave 32 q-rows; staging/barrier cost per unit
// work halved vs QBLK=128; per-wave early-skip of fully-masked KV tiles.
__global__ __launch_bounds__(512) void attn(const unsigned short* __restrict__ Qg,
                                            const unsigned short* __restrict__ Kg,
                                            const unsigned short* __restrict__ Vg,
                                            unsigned short* __restrict__ ctx) {
    __shared__ __attribute__((aligned(16))) unsigned short Ks[64][72];
    __shared__ __attribute__((aligned(16))) unsigned short Vs[64][72];
    __shared__ __attribute__((aligned(16))) unsigned short Pl[256][76];

    const int tid = threadIdx.x, lane = tid & 63, w = tid >> 6;   // w = 0..7
    const int wq = w * 32;
    const int lg = lane >> 4;
    const int ll = lane & 15;
    const int bh = blockIdx.x;
    const int q0 = (gridDim.y - 1 - blockIdx.y) * 256;   // heavy tiles first (LPT)
    const unsigned short* Qh = Qg + (size_t)bh * TSEQ * HD;
    const unsigned short* Kh = Kg + (size_t)bh * TSEQ * HD;
    const unsigned short* Vh = Vg + (size_t)bh * HD * TSEQ;

    short8 qf[2][2];
#pragma unroll
    for (int rb = 0; rb < 2; rb++)
#pragma unroll
        for (int ks = 0; ks < 2; ks++)
            qf[rb][ks] = *(const short8*)(Qh + (size_t)(q0 + wq + rb * 16 + ll) * HD + ks * 32 + lg * 8);

    float mrun[2] = {-1e30f, -1e30f}, lrun[2] = {0.f, 0.f};
    const f32x4 zerov = {0.f, 0.f, 0.f, 0.f};
    f32x4 o_t[2][4];
#pragma unroll
    for (int rb = 0; rb < 2; rb++)
#pragma unroll
        for (int db = 0; db < 4; db++) o_t[rb][db] = zerov;

    // staging: 512 threads cover K[64][64] and Vt[64][64] with 1 load each
    const int sr = tid >> 3;           // 0..63
    const int sc = (tid & 7) * 8;      // 0..56
    short8 kreg, vreg;
    kreg = *(const short8*)(Kh + (size_t)sr * HD + sc);
    vreg = *(const short8*)(Vh + (size_t)sr * TSEQ + sc);

    const int nkv = q0 / 64 + 4;
    for (int kt = 0; kt < nkv; kt++) {
        const int kv0 = kt * 64;
        __builtin_amdgcn_s_barrier();
        __builtin_amdgcn_sched_barrier(0);
        *(short8*)&Ks[sr][sc] = kreg;
        *(short8*)&Vs[sr][sc] = vreg;
        if (kt + 1 < nkv) {     // next tile's loads stay in flight across the barrier
            const int nv0 = kv0 + 64;
            kreg = *(const short8*)(Kh + (size_t)(nv0 + sr) * HD + sc);
            vreg = *(const short8*)(Vh + (size_t)sr * TSEQ + nv0 + sc);
        }
        __builtin_amdgcn_sched_barrier(0);
        asm volatile("s_waitcnt lgkmcnt(0)" ::: "memory");
        __builtin_amdgcn_s_barrier();
        __builtin_amdgcn_sched_barrier(0);

        // per-wave skip: this wave's rows [q0+wq, q0+wq+31] all < kv0 -> fully masked
        if (kv0 > q0 + wq + 31) continue;

        short8 af0[4], af1[4];
#pragma unroll
        for (int cb = 0; cb < 4; cb++) {
            af0[cb] = *(const short8*)&Ks[cb * 16 + ll][lg * 8];
            af1[cb] = *(const short8*)&Ks[cb * 16 + ll][32 + lg * 8];
        }
        f32x4 st[2][4];
#pragma unroll
        for (int rb = 0; rb < 2; rb++)
#pragma unroll
            for (int cb = 0; cb < 4; cb++)
                st[rb][cb] = __builtin_amdgcn_mfma_f32_16x16x32_bf16(af0[cb], qf[rb][0], zerov, 0, 0, 0);
#pragma unroll
        for (int rb = 0; rb < 2; rb++)
#pragma unroll
            for (int cb = 0; cb < 4; cb++)
                st[rb][cb] = __builtin_amdgcn_mfma_f32_16x16x32_bf16(af1[cb], qf[rb][1], st[rb][cb], 0, 0, 0);

        if (kv0 + 63 > q0 + wq) {   // diagonal-crossing for this wave
#pragma unroll
            for (int rb = 0; rb < 2; rb++)
#pragma unroll
                for (int cb = 0; cb < 4; cb++)
#pragma unroll
                    for (int r = 0; r < 4; r++) {
                        int kvl = cb * 16 + lg * 4 + r;
                        int ql = wq + rb * 16 + ll;
                        if (kv0 + kvl > q0 + ql) st[rb][cb][r] = -1e30f;
                    }
        }

        float mx[2];
#pragma unroll
        for (int rb = 0; rb < 2; rb++) {
            float a0 = fmaxf(fmaxf(st[rb][0][0], st[rb][0][1]), fmaxf(st[rb][0][2], st[rb][0][3]));
            float a1 = fmaxf(fmaxf(st[rb][1][0], st[rb][1][1]), fmaxf(st[rb][1][2], st[rb][1][3]));
            float a2 = fmaxf(fmaxf(st[rb][2][0], st[rb][2][1]), fmaxf(st[rb][2][2], st[rb][2][3]));
            float a3 = fmaxf(fmaxf(st[rb][3][0], st[rb][3][1]), fmaxf(st[rb][3][2], st[rb][3][3]));
            float m = fmaxf(fmaxf(a0, a1), fmaxf(a2, a3));
            m = fmaxf(m, __shfl_xor(m, 16));
            m = fmaxf(m, __shfl_xor(m, 32));
            mx[rb] = m;
        }
        float need = fmaxf(mx[0] - mrun[0], mx[1] - mrun[1]);
        if (__any(need > 8.f)) {
#pragma unroll
            for (int rb = 0; rb < 2; rb++) {
                float mold = mrun[rb];
                float mn = fmaxf(mold, mx[rb]);
                float rs = __builtin_amdgcn_exp2f(mold - mn);
                mrun[rb] = mn;
                lrun[rb] *= rs;
#pragma unroll
                for (int db = 0; db < 4; db++)
#pragma unroll
                    for (int r = 0; r < 4; r++) o_t[rb][db][r] *= rs;
            }
        }
#pragma unroll
        for (int rb = 0; rb < 2; rb++) {
            float sum = 0.f;
#pragma unroll
            for (int cb = 0; cb < 4; cb++) {
                float p0 = __builtin_amdgcn_exp2f(st[rb][cb][0] - mrun[rb]);
                float p1 = __builtin_amdgcn_exp2f(st[rb][cb][1] - mrun[rb]);
                float p2 = __builtin_amdgcn_exp2f(st[rb][cb][2] - mrun[rb]);
                float p3 = __builtin_amdgcn_exp2f(st[rb][cb][3] - mrun[rb]);
                sum += (p0 + p1) + (p2 + p3);
                uint2 pw;
                pw.x = cvtpk(p0, p1);
                pw.y = cvtpk(p2, p3);
                *(uint2*)&Pl[wq + rb * 16 + ll][cb * 16 + lg * 4] = pw;
            }
            sum += __shfl_xor(sum, 16);
            sum += __shfl_xor(sum, 32);
            lrun[rb] += sum;
        }
        asm volatile("s_waitcnt lgkmcnt(0)" ::: "memory");
        __builtin_amdgcn_sched_barrier(0);

#pragma unroll
        for (int ks = 0; ks < 2; ks++) {
            short8 pa[2], va[4];
#pragma unroll
            for (int rb = 0; rb < 2; rb++)
                pa[rb] = *(const short8*)&Pl[wq + rb * 16 + ll][ks * 32 + lg * 8];
#pragma unroll
            for (int db = 0; db < 4; db++)
                va[db] = *(const short8*)&Vs[db * 16 + ll][ks * 32 + lg * 8];
#pragma unroll
            for (int rb = 0; rb < 2; rb++)
#pragma unroll
                for (int db = 0; db < 4; db++)
                    o_t[rb][db] = __builtin_amdgcn_mfma_f32_16x16x32_bf16(va[db], pa[rb], o_t[rb][db], 0, 0, 0);
        }
    }

    const int b = bh >> 4, h = bh & 15;
#pragma unroll
    for (int rb = 0; rb < 2; rb++) {
        float linv = 1.f / lrun[rb];
#pragma unroll
        for (int db = 0; db < 4; db++) {
            uint2 pw;
            pw.x = cvtpk(o_t[rb][db][0] * linv, o_t[rb][db][1] * linv);
            pw.y = cvtpk(o_t[rb][db][2] * linv, o_t[rb][db][3] * linv);
            *(uint2*)&Pl[wq + rb * 16 + ll][db * 16 + lg * 4] = pw;
        }
    }
    asm volatile("s_waitcnt lgkmcnt(0)" ::: "memory");
    __builtin_amdgcn_sched_barrier(0);
#pragma unroll
    for (int rb = 0; rb < 2; rb++)
#pragma unroll
        for (int half = 0; half < 2; half++) {
            short8 v = *(const short8*)&Pl[wq + rb * 16 + ll][half * 32 + lg * 8];
            size_t row = (size_t)(b * TSEQ + q0 + wq + rb * 16 + ll);
            *(short8*)(ctx + (row * NH + h) * HD + half * 32 + lg * 8) = v;
        }
}

extern "C" void kernel_launch(void* const* d_in, const int* in_sizes, int n_in,
                              void* d_out, int out_size, void* d_ws, size_t ws_size,
                              hipStream_t stream) {
    const float* x  = (const float*)d_in[0];
    const float* Wq = (const float*)d_in[1];
    const float* Wk = (const float*)d_in[2];
    const float* Wv = (const float*)d_in[3];
    const float* Wo = (const float*)d_in[4];
    const float* bo = (const float*)d_in[5];
    float* out = (float*)d_out;

    char* ws = (char*)d_ws;
    unsigned short* xb   = (unsigned short*)(ws);             // 16,777,216 B
    unsigned short* Wqb  = (unsigned short*)(ws + 16777216);
    unsigned short* Wkb  = (unsigned short*)(ws + 18874368);
    unsigned short* Wvb  = (unsigned short*)(ws + 20971520);
    unsigned short* Wob  = (unsigned short*)(ws + 23068672);
    unsigned short* Qb   = (unsigned short*)(ws + 25165824);  // [B,H,T,hd] bf16 (pre-scaled)
    unsigned short* Kb   = (unsigned short*)(ws + 41943040);  // [B,H,T,hd]
    unsigned short* Vtb  = (unsigned short*)(ws + 58720256);  // [B,H,hd,T]
    unsigned short* ctxb = (unsigned short*)(ws + 75497472);  // [B,T,H,hd]

    cast_f32_bf16<<<8192, 256, 0, stream>>>(x, xb, 2097152);
    cast_weights<<<4096, 256, 0, stream>>>(Wq, Wk, Wv, Wo, Wqb, Wkb, Wvb, Wob);

    gemm_qkv<<<dim3(64, 8, 3), 256, 0, stream>>>(xb, Wqb, Wkb, Wvb, Qb, Kb, Vtb);
    attn<<<dim3(64, 8), 512, 0, stream>>>(Qb, Kb, Vtb, ctxb);
    gemm_out<<<dim3(64, 8), 256, 0, stream>>>(ctxb, Wob, bo, out);
}

// Round 11
// 181.668 us; speedup vs baseline: 1.1436x; 1.0116x over previous
//
#include <hip/hip_runtime.h>

#define NH 16
#define HD 64
#define TSEQ 2048
#define DMODEL 1024

typedef __attribute__((ext_vector_type(8))) short short8;
typedef __attribute__((ext_vector_type(4))) float f32x4;

static __device__ __forceinline__ unsigned short f2bf(float f) {
    unsigned u = __builtin_bit_cast(unsigned, f);
    u += 0x7FFF + ((u >> 16) & 1);
    return (unsigned short)(u >> 16);
}

// packed f32x2 -> bf16x2 (low = a, high = b), single VALU op
static __device__ __forceinline__ unsigned cvtpk(float a, float b) {
    unsigned r;
    asm("v_cvt_pk_bf16_f32 %0, %1, %2" : "=v"(r) : "v"(a), "v"(b));
    return r;
}

// ---------------- cast f32 -> bf16 (vectorized) ----------------
__global__ __launch_bounds__(256) void cast_f32_bf16(const float* __restrict__ src,
                                                     unsigned short* __restrict__ dst, int n4) {
    int i = blockIdx.x * 256 + threadIdx.x;
    if (i >= n4) return;
    float4 v = reinterpret_cast<const float4*>(src)[i];
    ushort4 o;
    o.x = f2bf(v.x); o.y = f2bf(v.y); o.z = f2bf(v.z); o.w = f2bf(v.w);
    reinterpret_cast<ushort4*>(dst)[i] = o;
}

__global__ __launch_bounds__(256) void cast_weights(const float* __restrict__ Wq,
                                                    const float* __restrict__ Wk,
                                                    const float* __restrict__ Wv,
                                                    const float* __restrict__ Wo,
                                                    unsigned short* __restrict__ dq,
                                                    unsigned short* __restrict__ dk,
                                                    unsigned short* __restrict__ dv,
                                                    unsigned short* __restrict__ dwo) {
    int g = blockIdx.x >> 10;
    int i = (blockIdx.x & 1023) * 256 + threadIdx.x;
    const float* s = (g == 0) ? Wq : (g == 1) ? Wk : (g == 2) ? Wv : Wo;
    unsigned short* d = (g == 0) ? dq : (g == 1) ? dk : (g == 2) ? dv : dwo;
    float4 v = reinterpret_cast<const float4*>(s)[i];
    ushort4 o;
    o.x = f2bf(v.x); o.y = f2bf(v.y); o.z = f2bf(v.z); o.w = f2bf(v.w);
    reinterpret_cast<ushort4*>(d)[i] = o;
}

// ============ 256x128 GEMM mainloop: 512 threads, m97-style dbuf ============
// C[256x128] = A[M][1024] * Bt[N][1024]^T, bf16 in, f32 acc.
// 512 threads = 8 waves (4M x 2N), per-wave 64x64 (acc 4x4): 8 ds_read +
// 16 MFMA per wave-K-tile. LDS: A dbuf 2x[256][32] (32KB) + B dbuf (16KB)
// = 48KB. Hypothesis under test: waves/CU has been pinned at ~8 for all
// 256-thread configs (r5-r10, occupancy always ~25% regardless of LDS);
// 512-thread blocks double waves/block -> up to 16 waves/CU.
// Compiler-scheduled inner loop (no pinning) per m97's 874 TF precedent;
// plain __syncthreads dbuf. Partial XOR swizzle (row&3 on 16B units),
// rule-21 both-sides: ~4-way residual conflict on a non-binding DS pipe.
static __device__ __forceinline__ void gemm256_mainloop(
    const unsigned short* __restrict__ A, const unsigned short* __restrict__ Bt,
    int m0, int n0, unsigned short* As, unsigned short* Bs, f32x4 acc[4][4]) {
    const int tid = threadIdx.x, lane = tid & 63, w = tid >> 6;
    const int wr = w >> 1, wc = w & 1;      // 4M x 2N
    const int lg = lane >> 4, ll = lane & 15;
    const int strow = tid >> 2;             // 0..127
    const int su = tid & 3;                 // 16B unit within 64B row
    const int rx = ll & 3;                  // read-side XOR (== row&3 of frag rows)

    const f32x4 zero = {0.f, 0.f, 0.f, 0.f};
#pragma unroll
    for (int i = 0; i < 4; i++)
#pragma unroll
        for (int j = 0; j < 4; j++) acc[i][j] = zero;

    auto stage = [&](int kt, int buf) {
#pragma unroll
        for (int s = 0; s < 2; ++s) {       // A rows 0..255
            int row = s * 128 + strow;
            int gcol = kt * 32 + ((su ^ (row & 3)) * 8);
            __builtin_amdgcn_global_load_lds(
                (const __attribute__((address_space(1))) void*)(A + (size_t)(m0 + row) * DMODEL + gcol),
                (__attribute__((address_space(3))) void*)(As + buf * 8192 + row * 32 + su * 8), 16, 0, 0);
        }
        {                                   // B rows 0..127
            int row = strow;
            int gcol = kt * 32 + ((su ^ (row & 3)) * 8);
            __builtin_amdgcn_global_load_lds(
                (const __attribute__((address_space(1))) void*)(Bt + (size_t)(n0 + row) * DMODEL + gcol),
                (__attribute__((address_space(3))) void*)(Bs + buf * 4096 + row * 32 + su * 8), 16, 0, 0);
        }
    };

    stage(0, 0);
    __syncthreads();                        // tile0 ready (vmcnt drained by compiler)
    int buf = 0;
#pragma unroll 1
    for (int kt = 0; kt < 32; ++kt) {
        if (kt + 1 < 32) stage(kt + 1, buf ^ 1);   // in flight during compute
        short8 af[4], bf[4];
#pragma unroll
        for (int i = 0; i < 4; i++)
            af[i] = *(const short8*)(As + buf * 8192 + (wr * 64 + i * 16 + ll) * 32 + ((lg ^ rx) * 8));
#pragma unroll
        for (int j = 0; j < 4; j++)
            bf[j] = *(const short8*)(Bs + buf * 4096 + (wc * 64 + j * 16 + ll) * 32 + ((lg ^ rx) * 8));
#pragma unroll
        for (int i = 0; i < 4; i++)
#pragma unroll
            for (int j = 0; j < 4; j++)
                acc[i][j] = __builtin_amdgcn_mfma_f32_16x16x32_bf16(af[i], bf[j], acc[i][j], 0, 0, 0);
        __syncthreads();                    // readers done + next stage landed
        buf ^= 1;
    }
}

// ---------------- QKV projection ----------------
#define QSCALE 0.180336880f
__global__ __launch_bounds__(512) void gemm_qkv(const unsigned short* __restrict__ xb,
                                                const unsigned short* __restrict__ Wqb,
                                                const unsigned short* __restrict__ Wkb,
                                                const unsigned short* __restrict__ Wvb,
                                                unsigned short* __restrict__ Q,
                                                unsigned short* __restrict__ K,
                                                unsigned short* __restrict__ Vt) {
    __shared__ __attribute__((aligned(16))) unsigned short As[2 * 256 * 32];
    __shared__ __attribute__((aligned(16))) unsigned short Bs[2 * 128 * 32];
    const int m0 = blockIdx.x * 256;
    const int n0 = blockIdx.y * 128;
    const int z = blockIdx.z;
    const unsigned short* Bt = (z == 0) ? Wqb : ((z == 1) ? Wkb : Wvb);
    unsigned short* out = (z == 0) ? Q : ((z == 1) ? K : Vt);

    f32x4 acc[4][4];
    gemm256_mainloop(xb, Bt, m0, n0, As, Bs, acc);

    const int lane = threadIdx.x & 63, w = threadIdx.x >> 6;
    const int wr = w >> 1, wc = w & 1;
    const int lg = lane >> 4, ll = lane & 15;
    const float sc = (z == 0) ? QSCALE : 1.0f;
    if (z == 2) {
        // Vt[(b*NH+h)*HD+d][t]: 4 consecutive r = 4 consecutive t -> ushort4
#pragma unroll
        for (int i = 0; i < 4; i++)
#pragma unroll
            for (int j = 0; j < 4; j++) {
                int row0 = m0 + wr * 64 + i * 16 + lg * 4;      // aligned to 4
                int col = n0 + wc * 64 + j * 16 + ll;
                int b = row0 >> 11, t0 = row0 & 2047;
                int h = col >> 6, d = col & 63;
                ushort4 v4;
                v4.x = f2bf(acc[i][j][0]); v4.y = f2bf(acc[i][j][1]);
                v4.z = f2bf(acc[i][j][2]); v4.w = f2bf(acc[i][j][3]);
                *(ushort4*)&Vt[(((size_t)(b * NH + h)) * HD + d) * TSEQ + t0] = v4;
            }
    } else {
#pragma unroll
        for (int i = 0; i < 4; i++)
#pragma unroll
            for (int j = 0; j < 4; j++)
#pragma unroll
                for (int r = 0; r < 4; r++) {
                    int row = m0 + wr * 64 + i * 16 + lg * 4 + r;   // b*2048 + t
                    int col = n0 + wc * 64 + j * 16 + ll;           // h*64 + d
                    int b = row >> 11, t = row & 2047;
                    int h = col >> 6, d = col & 63;
                    out[(((size_t)(b * NH + h)) * TSEQ + t) * HD + d] = f2bf(acc[i][j][r] * sc);
                }
    }
}

// ---------------- output projection ----------------
__global__ __launch_bounds__(512) void gemm_out(const unsigned short* __restrict__ ctx,
                                                const unsigned short* __restrict__ Wob,
                                                const float* __restrict__ bo,
                                                float* __restrict__ out) {
    __shared__ __attribute__((aligned(16))) unsigned short As[2 * 256 * 32];
    __shared__ __attribute__((aligned(16))) unsigned short Bs[2 * 128 * 32];
    const int m0 = blockIdx.x * 256;
    const int n0 = blockIdx.y * 128;

    f32x4 acc[4][4];
    gemm256_mainloop(ctx, Wob, m0, n0, As, Bs, acc);

    const int lane = threadIdx.x & 63, w = threadIdx.x >> 6;
    const int wr = w >> 1, wc = w & 1;
    const int lg = lane >> 4, ll = lane & 15;
#pragma unroll
    for (int i = 0; i < 4; i++)
#pragma unroll
        for (int j = 0; j < 4; j++) {
            int col = n0 + wc * 64 + j * 16 + ll;
            float bias = bo[col];
#pragma unroll
            for (int r = 0; r < 4; r++) {
                int row = m0 + wr * 64 + i * 16 + lg * 4 + r;
                out[(size_t)row * DMODEL + col] = acc[i][j][r] + bias;
            }
        }
}

// ---------------- flash attention (causal), Q-tile 256, KV-tile 64, 8 waves ----------------
// S^T structure: per-wave 32 q-rows; in-register softmax + 2 shfl; P via
// cvt_pk + b64 writes; O^T = mfma(Vt,P); per-wave skip of masked tiles.
__global__ __launch_bounds__(512) void attn(const unsigned short* __restrict__ Qg,
                                            const unsigned short* __restrict__ Kg,
                                            const unsigned short* __restrict__ Vg,
                                            unsigned short* __restrict__ ctx) {
    __shared__ __attribute__((aligned(16))) unsigned short Ks[64][72];
    __shared__ __attribute__((aligned(16))) unsigned short Vs[64][72];
    __shared__ __attribute__((aligned(16))) unsigned short Pl[256][76];

    const int tid = threadIdx.x, lane = tid & 63, w = tid >> 6;   // w = 0..7
    const int wq = w * 32;
    const int lg = lane >> 4;
    const int ll = lane & 15;
    const int bh = blockIdx.x;
    const int q0 = (gridDim.y - 1 - blockIdx.y) * 256;   // heavy tiles first (LPT)
    const unsigned short* Qh = Qg + (size_t)bh * TSEQ * HD;
    const unsigned short* Kh = Kg + (size_t)bh * TSEQ * HD;
    const unsigned short* Vh = Vg + (size_t)bh * HD * TSEQ;

    short8 qf[2][2];
#pragma unroll
    for (int rb = 0; rb < 2; rb++)
#pragma unroll
        for (int ks = 0; ks < 2; ks++)
            qf[rb][ks] = *(const short8*)(Qh + (size_t)(q0 + wq + rb * 16 + ll) * HD + ks * 32 + lg * 8);

    float mrun[2] = {-1e30f, -1e30f}, lrun[2] = {0.f, 0.f};
    const f32x4 zerov = {0.f, 0.f, 0.f, 0.f};
    f32x4 o_t[2][4];
#pragma unroll
    for (int rb = 0; rb < 2; rb++)
#pragma unroll
        for (int db = 0; db < 4; db++) o_t[rb][db] = zerov;

    const int sr = tid >> 3;           // 0..63
    const int sc = (tid & 7) * 8;      // 0..56
    short8 kreg, vreg;
    kreg = *(const short8*)(Kh + (size_t)sr * HD + sc);
    vreg = *(const short8*)(Vh + (size_t)sr * TSEQ + sc);

    const int nkv = q0 / 64 + 4;
    for (int kt = 0; kt < nkv; kt++) {
        const int kv0 = kt * 64;
        __builtin_amdgcn_s_barrier();
        __builtin_amdgcn_sched_barrier(0);
        *(short8*)&Ks[sr][sc] = kreg;
        *(short8*)&Vs[sr][sc] = vreg;
        if (kt + 1 < nkv) {
            const int nv0 = kv0 + 64;
            kreg = *(const short8*)(Kh + (size_t)(nv0 + sr) * HD + sc);
            vreg = *(const short8*)(Vh + (size_t)sr * TSEQ + nv0 + sc);
        }
        __builtin_amdgcn_sched_barrier(0);
        asm volatile("s_waitcnt lgkmcnt(0)" ::: "memory");
        __builtin_amdgcn_s_barrier();
        __builtin_amdgcn_sched_barrier(0);

        if (kv0 > q0 + wq + 31) continue;   // fully masked for this wave

        short8 af0[4], af1[4];
#pragma unroll
        for (int cb = 0; cb < 4; cb++) {
            af0[cb] = *(const short8*)&Ks[cb * 16 + ll][lg * 8];
            af1[cb] = *(const short8*)&Ks[cb * 16 + ll][32 + lg * 8];
        }
        f32x4 st[2][4];
#pragma unroll
        for (int rb = 0; rb < 2; rb++)
#pragma unroll
            for (int cb = 0; cb < 4; cb++)
                st[rb][cb] = __builtin_amdgcn_mfma_f32_16x16x32_bf16(af0[cb], qf[rb][0], zerov, 0, 0, 0);
#pragma unroll
        for (int rb = 0; rb < 2; rb++)
#pragma unroll
            for (int cb = 0; cb < 4; cb++)
                st[rb][cb] = __builtin_amdgcn_mfma_f32_16x16x32_bf16(af1[cb], qf[rb][1], st[rb][cb], 0, 0, 0);

        if (kv0 + 63 > q0 + wq) {
#pragma unroll
            for (int rb = 0; rb < 2; rb++)
#pragma unroll
                for (int cb = 0; cb < 4; cb++)
#pragma unroll
                    for (int r = 0; r < 4; r++) {
                        int kvl = cb * 16 + lg * 4 + r;
                        int ql = wq + rb * 16 + ll;
                        if (kv0 + kvl > q0 + ql) st[rb][cb][r] = -1e30f;
                    }
        }

        float mx[2];
#pragma unroll
        for (int rb = 0; rb < 2; rb++) {
            float a0 = fmaxf(fmaxf(st[rb][0][0], st[rb][0][1]), fmaxf(st[rb][0][2], st[rb][0][3]));
            float a1 = fmaxf(fmaxf(st[rb][1][0], st[rb][1][1]), fmaxf(st[rb][1][2], st[rb][1][3]));
            float a2 = fmaxf(fmaxf(st[rb][2][0], st[rb][2][1]), fmaxf(st[rb][2][2], st[rb][2][3]));
            float a3 = fmaxf(fmaxf(st[rb][3][0], st[rb][3][1]), fmaxf(st[rb][3][2], st[rb][3][3]));
            float m = fmaxf(fmaxf(a0, a1), fmaxf(a2, a3));
            m = fmaxf(m, __shfl_xor(m, 16));
            m = fmaxf(m, __shfl_xor(m, 32));
            mx[rb] = m;
        }
        float need = fmaxf(mx[0] - mrun[0], mx[1] - mrun[1]);
        if (__any(need > 8.f)) {
#pragma unroll
            for (int rb = 0; rb < 2; rb++) {
                float mold = mrun[rb];
                float mn = fmaxf(mold, mx[rb]);
                float rs = __builtin_amdgcn_exp2f(mold - mn);
                mrun[rb] = mn;
                lrun[rb] *= rs;
#pragma unroll
                for (int db = 0; db < 4; db++)
#pragma unroll
                    for (int r = 0; r < 4; r++) o_t[rb][db][r] *= rs;
            }
        }
#pragma unroll
        for (int rb = 0; rb < 2; rb++) {
            float sum = 0.f;
#pragma unroll
            for (int cb = 0; cb < 4; cb++) {
                float p0 = __builtin_amdgcn_exp2f(st[rb][cb][0] - mrun[rb]);
                float p1 = __builtin_amdgcn_exp2f(st[rb][cb][1] - mrun[rb]);
                float p2 = __builtin_amdgcn_exp2f(st[rb][cb][2] - mrun[rb]);
                float p3 = __builtin_amdgcn_exp2f(st[rb][cb][3] - mrun[rb]);
                sum += (p0 + p1) + (p2 + p3);
                uint2 pw;
                pw.x = cvtpk(p0, p1);
                pw.y = cvtpk(p2, p3);
                *(uint2*)&Pl[wq + rb * 16 + ll][cb * 16 + lg * 4] = pw;
            }
            sum += __shfl_xor(sum, 16);
            sum += __shfl_xor(sum, 32);
            lrun[rb] += sum;
        }
        asm volatile("s_waitcnt lgkmcnt(0)" ::: "memory");
        __builtin_amdgcn_sched_barrier(0);

#pragma unroll
        for (int ks = 0; ks < 2; ks++) {
            short8 pa[2], va[4];
#pragma unroll
            for (int rb = 0; rb < 2; rb++)
                pa[rb] = *(const short8*)&Pl[wq + rb * 16 + ll][ks * 32 + lg * 8];
#pragma unroll
            for (int db = 0; db < 4; db++)
                va[db] = *(const short8*)&Vs[db * 16 + ll][ks * 32 + lg * 8];
#pragma unroll
            for (int rb = 0; rb < 2; rb++)
#pragma unroll
                for (int db = 0; db < 4; db++)
                    o_t[rb][db] = __builtin_amdgcn_mfma_f32_16x16x32_bf16(va[db], pa[rb], o_t[rb][db], 0, 0, 0);
        }
    }

    const int b = bh >> 4, h = bh & 15;
#pragma unroll
    for (int rb = 0; rb < 2; rb++) {
        float linv = 1.f / lrun[rb];
#pragma unroll
        for (int db = 0; db < 4; db++) {
            uint2 pw;
            pw.x = cvtpk(o_t[rb][db][0] * linv, o_t[rb][db][1] * linv);
            pw.y = cvtpk(o_t[rb][db][2] * linv, o_t[rb][db][3] * linv);
            *(uint2*)&Pl[wq + rb * 16 + ll][db * 16 + lg * 4] = pw;
        }
    }
    asm volatile("s_waitcnt lgkmcnt(0)" ::: "memory");
    __builtin_amdgcn_sched_barrier(0);
#pragma unroll
    for (int rb = 0; rb < 2; rb++)
#pragma unroll
        for (int half = 0; half < 2; half++) {
            short8 v = *(const short8*)&Pl[wq + rb * 16 + ll][half * 32 + lg * 8];
            size_t row = (size_t)(b * TSEQ + q0 + wq + rb * 16 + ll);
            *(short8*)(ctx + (row * NH + h) * HD + half * 32 + lg * 8) = v;
        }
}

extern "C" void kernel_launch(void* const* d_in, const int* in_sizes, int n_in,
                              void* d_out, int out_size, void* d_ws, size_t ws_size,
                              hipStream_t stream) {
    const float* x  = (const float*)d_in[0];
    const float* Wq = (const float*)d_in[1];
    const float* Wk = (const float*)d_in[2];
    const float* Wv = (const float*)d_in[3];
    const float* Wo = (const float*)d_in[4];
    const float* bo = (const float*)d_in[5];
    float* out = (float*)d_out;

    char* ws = (char*)d_ws;
    unsigned short* xb   = (unsigned short*)(ws);             // 16,777,216 B
    unsigned short* Wqb  = (unsigned short*)(ws + 16777216);
    unsigned short* Wkb  = (unsigned short*)(ws + 18874368);
    unsigned short* Wvb  = (unsigned short*)(ws + 20971520);
    unsigned short* Wob  = (unsigned short*)(ws + 23068672);
    unsigned short* Qb   = (unsigned short*)(ws + 25165824);  // [B,H,T,hd] bf16 (pre-scaled)
    unsigned short* Kb   = (unsigned short*)(ws + 41943040);  // [B,H,T,hd]
    unsigned short* Vtb  = (unsigned short*)(ws + 58720256);  // [B,H,hd,T]
    unsigned short* ctxb = (unsigned short*)(ws + 75497472);  // [B,T,H,hd]

    cast_f32_bf16<<<8192, 256, 0, stream>>>(x, xb, 2097152);
    cast_weights<<<4096, 256, 0, stream>>>(Wq, Wk, Wv, Wo, Wqb, Wkb, Wvb, Wob);

    gemm_qkv<<<dim3(32, 8, 3), 512, 0, stream>>>(xb, Wqb, Wkb, Wvb, Qb, Kb, Vtb);
    attn<<<dim3(64, 8), 512, 0, stream>>>(Qb, Kb, Vtb, ctxb);
    gemm_out<<<dim3(32, 8), 512, 0, stream>>>(ctxb, Wob, bo, out);
}

// Round 12
// 169.715 us; speedup vs baseline: 1.2241x; 1.0704x over previous
//
#include <hip/hip_runtime.h>

#define NH 16
#define HD 64
#define TSEQ 2048
#define DMODEL 1024

typedef __attribute__((ext_vector_type(8))) short short8;
typedef __attribute__((ext_vector_type(4))) float f32x4;

static __device__ __forceinline__ unsigned short f2bf(float f) {
    unsigned u = __builtin_bit_cast(unsigned, f);
    u += 0x7FFF + ((u >> 16) & 1);
    return (unsigned short)(u >> 16);
}

// packed f32x2 -> bf16x2 (low = a, high = b), single VALU op
static __device__ __forceinline__ unsigned cvtpk(float a, float b) {
    unsigned r;
    asm("v_cvt_pk_bf16_f32 %0, %1, %2" : "=v"(r) : "v"(a), "v"(b));
    return r;
}

// ---------------- cast f32 -> bf16 (vectorized) ----------------
__global__ __launch_bounds__(256) void cast_f32_bf16(const float* __restrict__ src,
                                                     unsigned short* __restrict__ dst, int n4) {
    int i = blockIdx.x * 256 + threadIdx.x;
    if (i >= n4) return;
    float4 v = reinterpret_cast<const float4*>(src)[i];
    ushort4 o;
    o.x = f2bf(v.x); o.y = f2bf(v.y); o.z = f2bf(v.z); o.w = f2bf(v.w);
    reinterpret_cast<ushort4*>(dst)[i] = o;
}

__global__ __launch_bounds__(256) void cast_weights(const float* __restrict__ Wq,
                                                    const float* __restrict__ Wk,
                                                    const float* __restrict__ Wv,
                                                    const float* __restrict__ Wo,
                                                    unsigned short* __restrict__ dq,
                                                    unsigned short* __restrict__ dk,
                                                    unsigned short* __restrict__ dv,
                                                    unsigned short* __restrict__ dwo) {
    int g = blockIdx.x >> 10;
    int i = (blockIdx.x & 1023) * 256 + threadIdx.x;
    const float* s = (g == 0) ? Wq : (g == 1) ? Wk : (g == 2) ? Wv : Wo;
    unsigned short* d = (g == 0) ? dq : (g == 1) ? dk : (g == 2) ? dv : dwo;
    float4 v = reinterpret_cast<const float4*>(s)[i];
    ushort4 o;
    o.x = f2bf(v.x); o.y = f2bf(v.y); o.z = f2bf(v.z); o.w = f2bf(v.w);
    reinterpret_cast<ushort4*>(d)[i] = o;
}

// ============ 256x128 GEMM mainloop: 512 threads, 3-ring, counted vmcnt ============
// C[256x128] = A[M][1024] * Bt[N][1024]^T, bf16 in, f32 acc.
// 512 threads = 8 waves (4M x 2N), per-wave 64x64 (acc 4x4).
// Composition of two validated pieces: (a) 512-thread blocks at <=72KB LDS
// -> 2 blocks/CU TLP (r11: 86->72 us); (b) 3-ring + kt+2 prefetch + counted
// vmcnt -> ~700cyc latency cover (r9's schedule, which ran at 1 block/CU).
// LDS: A 3-ring [256][32] (48KB) + B 3-ring [128][32] (24KB) = 72KB.
// Per K-tile: ds_read frags -> issue stage(kt+2) (3 loads/thread) ->
// lgkmcnt(0) -> 16-MFMA setprio cluster -> vmcnt(3) (kt+1 landed, kt+2 in
// flight) -> ONE s_barrier. Slot (kt+2)%3 was last read at kt-1, before the
// kt-1 barrier -> no write-before-read race. Partial XOR swizzle (row&3,
// 16B units) both-sides; residual conflicts proven non-binding (r8 vs r11).
static __device__ __forceinline__ void gemm256_mainloop(
    const unsigned short* __restrict__ A, const unsigned short* __restrict__ Bt,
    int m0, int n0, unsigned short* As, unsigned short* Bs, f32x4 acc[4][4]) {
    const int tid = threadIdx.x, lane = tid & 63, w = tid >> 6;
    const int wr = w >> 1, wc = w & 1;      // 4M x 2N
    const int lg = lane >> 4, ll = lane & 15;
    const int strow = tid >> 2;             // 0..127
    const int su = tid & 3;                 // 16B unit within 64B row
    const int rx = ll & 3;                  // read-side XOR (== row&3 of frag rows)

    const f32x4 zero = {0.f, 0.f, 0.f, 0.f};
#pragma unroll
    for (int i = 0; i < 4; i++)
#pragma unroll
        for (int j = 0; j < 4; j++) acc[i][j] = zero;

    auto stage = [&](int kt, int slot) {    // 3 loads/thread: 2 A + 1 B
#pragma unroll
        for (int s = 0; s < 2; ++s) {       // A rows 0..255
            int row = s * 128 + strow;
            int gcol = kt * 32 + ((su ^ (row & 3)) * 8);
            __builtin_amdgcn_global_load_lds(
                (const __attribute__((address_space(1))) void*)(A + (size_t)(m0 + row) * DMODEL + gcol),
                (__attribute__((address_space(3))) void*)(As + slot * 8192 + row * 32 + su * 8), 16, 0, 0);
        }
        {                                   // B rows 0..127
            int row = strow;
            int gcol = kt * 32 + ((su ^ (row & 3)) * 8);
            __builtin_amdgcn_global_load_lds(
                (const __attribute__((address_space(1))) void*)(Bt + (size_t)(n0 + row) * DMODEL + gcol),
                (__attribute__((address_space(3))) void*)(Bs + slot * 4096 + row * 32 + su * 8), 16, 0, 0);
        }
    };

    // prologue: tiles 0,1; wait tile0 (tile1's 3 loads stay in flight)
    stage(0, 0);
    stage(1, 1);
    asm volatile("s_waitcnt vmcnt(3)" ::: "memory");
    __builtin_amdgcn_s_barrier();
    __builtin_amdgcn_sched_barrier(0);

    int pb = 0;
#pragma unroll 1
    for (int kt = 0; kt < 32; ++kt) {
        short8 af[4], bf[4];
#pragma unroll
        for (int i = 0; i < 4; i++)
            af[i] = *(const short8*)(As + pb * 8192 + (wr * 64 + i * 16 + ll) * 32 + ((lg ^ rx) * 8));
#pragma unroll
        for (int j = 0; j < 4; j++)
            bf[j] = *(const short8*)(Bs + pb * 4096 + (wc * 64 + j * 16 + ll) * 32 + ((lg ^ rx) * 8));
        const int pn = (pb + 2 >= 3) ? (pb - 1) : (pb + 2);
        if (kt + 2 < 32) stage(kt + 2, pn);

        asm volatile("s_waitcnt lgkmcnt(0)" ::: "memory");
        __builtin_amdgcn_sched_barrier(0);
        __builtin_amdgcn_s_setprio(1);
#pragma unroll
        for (int i = 0; i < 4; i++)
#pragma unroll
            for (int j = 0; j < 4; j++)
                acc[i][j] = __builtin_amdgcn_mfma_f32_16x16x32_bf16(af[i], bf[j], acc[i][j], 0, 0, 0);
        __builtin_amdgcn_s_setprio(0);
        __builtin_amdgcn_sched_barrier(0);
        if (kt + 2 < 32) {
            asm volatile("s_waitcnt vmcnt(3)" ::: "memory");   // kt+1 landed; kt+2 in flight
        } else {
            asm volatile("s_waitcnt vmcnt(0)" ::: "memory");   // tail drain
        }
        __builtin_amdgcn_s_barrier();
        __builtin_amdgcn_sched_barrier(0);
        pb = (pb + 1 >= 3) ? 0 : (pb + 1);
    }
}

// ---------------- QKV projection ----------------
#define QSCALE 0.180336880f
__global__ __launch_bounds__(512) void gemm_qkv(const unsigned short* __restrict__ xb,
                                                const unsigned short* __restrict__ Wqb,
                                                const unsigned short* __restrict__ Wkb,
                                                const unsigned short* __restrict__ Wvb,
                                                unsigned short* __restrict__ Q,
                                                unsigned short* __restrict__ K,
                                                unsigned short* __restrict__ Vt) {
    __shared__ __attribute__((aligned(16))) unsigned short As[3 * 256 * 32];
    __shared__ __attribute__((aligned(16))) unsigned short Bs[3 * 128 * 32];
    const int m0 = blockIdx.x * 256;
    const int n0 = blockIdx.y * 128;
    const int z = blockIdx.z;
    const unsigned short* Bt = (z == 0) ? Wqb : ((z == 1) ? Wkb : Wvb);
    unsigned short* out = (z == 0) ? Q : ((z == 1) ? K : Vt);

    f32x4 acc[4][4];
    gemm256_mainloop(xb, Bt, m0, n0, As, Bs, acc);

    const int lane = threadIdx.x & 63, w = threadIdx.x >> 6;
    const int wr = w >> 1, wc = w & 1;
    const int lg = lane >> 4, ll = lane & 15;
    const float sc = (z == 0) ? QSCALE : 1.0f;
    if (z == 2) {
        // Vt[(b*NH+h)*HD+d][t]: 4 consecutive r = 4 consecutive t -> ushort4
#pragma unroll
        for (int i = 0; i < 4; i++)
#pragma unroll
            for (int j = 0; j < 4; j++) {
                int row0 = m0 + wr * 64 + i * 16 + lg * 4;      // aligned to 4
                int col = n0 + wc * 64 + j * 16 + ll;
                int b = row0 >> 11, t0 = row0 & 2047;
                int h = col >> 6, d = col & 63;
                ushort4 v4;
                v4.x = f2bf(acc[i][j][0]); v4.y = f2bf(acc[i][j][1]);
                v4.z = f2bf(acc[i][j][2]); v4.w = f2bf(acc[i][j][3]);
                *(ushort4*)&Vt[(((size_t)(b * NH + h)) * HD + d) * TSEQ + t0] = v4;
            }
    } else {
#pragma unroll
        for (int i = 0; i < 4; i++)
#pragma unroll
            for (int j = 0; j < 4; j++)
#pragma unroll
                for (int r = 0; r < 4; r++) {
                    int row = m0 + wr * 64 + i * 16 + lg * 4 + r;   // b*2048 + t
                    int col = n0 + wc * 64 + j * 16 + ll;           // h*64 + d
                    int b = row >> 11, t = row & 2047;
                    int h = col >> 6, d = col & 63;
                    out[(((size_t)(b * NH + h)) * TSEQ + t) * HD + d] = f2bf(acc[i][j][r] * sc);
                }
    }
}

// ---------------- output projection ----------------
__global__ __launch_bounds__(512) void gemm_out(const unsigned short* __restrict__ ctx,
                                                const unsigned short* __restrict__ Wob,
                                                const float* __restrict__ bo,
                                                float* __restrict__ out) {
    __shared__ __attribute__((aligned(16))) unsigned short As[3 * 256 * 32];
    __shared__ __attribute__((aligned(16))) unsigned short Bs[3 * 128 * 32];
    const int m0 = blockIdx.x * 256;
    const int n0 = blockIdx.y * 128;

    f32x4 acc[4][4];
    gemm256_mainloop(ctx, Wob, m0, n0, As, Bs, acc);

    const int lane = threadIdx.x & 63, w = threadIdx.x >> 6;
    const int wr = w >> 1, wc = w & 1;
    const int lg = lane >> 4, ll = lane & 15;
#pragma unroll
    for (int i = 0; i < 4; i++)
#pragma unroll
        for (int j = 0; j < 4; j++) {
            int col = n0 + wc * 64 + j * 16 + ll;
            float bias = bo[col];
#pragma unroll
            for (int r = 0; r < 4; r++) {
                int row = m0 + wr * 64 + i * 16 + lg * 4 + r;
                out[(size_t)row * DMODEL + col] = acc[i][j][r] + bias;
            }
        }
}

// ---------------- flash attention (causal), Q-tile 256, KV-tile 64, 8 waves ----------------
// S^T structure: per-wave 32 q-rows; in-register softmax + 2 shfl; P via
// cvt_pk + b64 writes; O^T = mfma(Vt,P); per-wave skip of masked tiles.
__global__ __launch_bounds__(512) void attn(const unsigned short* __restrict__ Qg,
                                            const unsigned short* __restrict__ Kg,
                                            const unsigned short* __restrict__ Vg,
                                            unsigned short* __restrict__ ctx) {
    __shared__ __attribute__((aligned(16))) unsigned short Ks[64][72];
    __shared__ __attribute__((aligned(16))) unsigned short Vs[64][72];
    __shared__ __attribute__((aligned(16))) unsigned short Pl[256][76];

    const int tid = threadIdx.x, lane = tid & 63, w = tid >> 6;   // w = 0..7
    const int wq = w * 32;
    const int lg = lane >> 4;
    const int ll = lane & 15;
    const int bh = blockIdx.x;
    const int q0 = (gridDim.y - 1 - blockIdx.y) * 256;   // heavy tiles first (LPT)
    const unsigned short* Qh = Qg + (size_t)bh * TSEQ * HD;
    const unsigned short* Kh = Kg + (size_t)bh * TSEQ * HD;
    const unsigned short* Vh = Vg + (size_t)bh * HD * TSEQ;

    short8 qf[2][2];
#pragma unroll
    for (int rb = 0; rb < 2; rb++)
#pragma unroll
        for (int ks = 0; ks < 2; ks++)
            qf[rb][ks] = *(const short8*)(Qh + (size_t)(q0 + wq + rb * 16 + ll) * HD + ks * 32 + lg * 8);

    float mrun[2] = {-1e30f, -1e30f}, lrun[2] = {0.f, 0.f};
    const f32x4 zerov = {0.f, 0.f, 0.f, 0.f};
    f32x4 o_t[2][4];
#pragma unroll
    for (int rb = 0; rb < 2; rb++)
#pragma unroll
        for (int db = 0; db < 4; db++) o_t[rb][db] = zerov;

    const int sr = tid >> 3;           // 0..63
    const int sc = (tid & 7) * 8;      // 0..56
    short8 kreg, vreg;
    kreg = *(const short8*)(Kh + (size_t)sr * HD + sc);
    vreg = *(const short8*)(Vh + (size_t)sr * TSEQ + sc);

    const int nkv = q0 / 64 + 4;
    for (int kt = 0; kt < nkv; kt++) {
        const int kv0 = kt * 64;
        __builtin_amdgcn_s_barrier();
        __builtin_amdgcn_sched_barrier(0);
        *(short8*)&Ks[sr][sc] = kreg;
        *(short8*)&Vs[sr][sc] = vreg;
        if (kt + 1 < nkv) {
            const int nv0 = kv0 + 64;
            kreg = *(const short8*)(Kh + (size_t)(nv0 + sr) * HD + sc);
            vreg = *(const short8*)(Vh + (size_t)sr * TSEQ + nv0 + sc);
        }
        __builtin_amdgcn_sched_barrier(0);
        asm volatile("s_waitcnt lgkmcnt(0)" ::: "memory");
        __builtin_amdgcn_s_barrier();
        __builtin_amdgcn_sched_barrier(0);

        if (kv0 > q0 + wq + 31) continue;   // fully masked for this wave

        short8 af0[4], af1[4];
#pragma unroll
        for (int cb = 0; cb < 4; cb++) {
            af0[cb] = *(const short8*)&Ks[cb * 16 + ll][lg * 8];
            af1[cb] = *(const short8*)&Ks[cb * 16 + ll][32 + lg * 8];
        }
        f32x4 st[2][4];
#pragma unroll
        for (int rb = 0; rb < 2; rb++)
#pragma unroll
            for (int cb = 0; cb < 4; cb++)
                st[rb][cb] = __builtin_amdgcn_mfma_f32_16x16x32_bf16(af0[cb], qf[rb][0], zerov, 0, 0, 0);
#pragma unroll
        for (int rb = 0; rb < 2; rb++)
#pragma unroll
            for (int cb = 0; cb < 4; cb++)
                st[rb][cb] = __builtin_amdgcn_mfma_f32_16x16x32_bf16(af1[cb], qf[rb][1], st[rb][cb], 0, 0, 0);

        if (kv0 + 63 > q0 + wq) {
#pragma unroll
            for (int rb = 0; rb < 2; rb++)
#pragma unroll
                for (int cb = 0; cb < 4; cb++)
#pragma unroll
                    for (int r = 0; r < 4; r++) {
                        int kvl = cb * 16 + lg * 4 + r;
                        int ql = wq + rb * 16 + ll;
                        if (kv0 + kvl > q0 + ql) st[rb][cb][r] = -1e30f;
                    }
        }

        float mx[2];
#pragma unroll
        for (int rb = 0; rb < 2; rb++) {
            float a0 = fmaxf(fmaxf(st[rb][0][0], st[rb][0][1]), fmaxf(st[rb][0][2], st[rb][0][3]));
            float a1 = fmaxf(fmaxf(st[rb][1][0], st[rb][1][1]), fmaxf(st[rb][1][2], st[rb][1][3]));
            float a2 = fmaxf(fmaxf(st[rb][2][0], st[rb][2][1]), fmaxf(st[rb][2][2], st[rb][2][3]));
            float a3 = fmaxf(fmaxf(st[rb][3][0], st[rb][3][1]), fmaxf(st[rb][3][2], st[rb][3][3]));
            float m = fmaxf(fmaxf(a0, a1), fmaxf(a2, a3));
            m = fmaxf(m, __shfl_xor(m, 16));
            m = fmaxf(m, __shfl_xor(m, 32));
            mx[rb] = m;
        }
        float need = fmaxf(mx[0] - mrun[0], mx[1] - mrun[1]);
        if (__any(need > 8.f)) {
#pragma unroll
            for (int rb = 0; rb < 2; rb++) {
                float mold = mrun[rb];
                float mn = fmaxf(mold, mx[rb]);
                float rs = __builtin_amdgcn_exp2f(mold - mn);
                mrun[rb] = mn;
                lrun[rb] *= rs;
#pragma unroll
                for (int db = 0; db < 4; db++)
#pragma unroll
                    for (int r = 0; r < 4; r++) o_t[rb][db][r] *= rs;
            }
        }
#pragma unroll
        for (int rb = 0; rb < 2; rb++) {
            float sum = 0.f;
#pragma unroll
            for (int cb = 0; cb < 4; cb++) {
                float p0 = __builtin_amdgcn_exp2f(st[rb][cb][0] - mrun[rb]);
                float p1 = __builtin_amdgcn_exp2f(st[rb][cb][1] - mrun[rb]);
                float p2 = __builtin_amdgcn_exp2f(st[rb][cb][2] - mrun[rb]);
                float p3 = __builtin_amdgcn_exp2f(st[rb][cb][3] - mrun[rb]);
                sum += (p0 + p1) + (p2 + p3);
                uint2 pw;
                pw.x = cvtpk(p0, p1);
                pw.y = cvtpk(p2, p3);
                *(uint2*)&Pl[wq + rb * 16 + ll][cb * 16 + lg * 4] = pw;
            }
            sum += __shfl_xor(sum, 16);
            sum += __shfl_xor(sum, 32);
            lrun[rb] += sum;
        }
        asm volatile("s_waitcnt lgkmcnt(0)" ::: "memory");
        __builtin_amdgcn_sched_barrier(0);

#pragma unroll
        for (int ks = 0; ks < 2; ks++) {
            short8 pa[2], va[4];
#pragma unroll
            for (int rb = 0; rb < 2; rb++)
                pa[rb] = *(const short8*)&Pl[wq + rb * 16 + ll][ks * 32 + lg * 8];
#pragma unroll
            for (int db = 0; db < 4; db++)
                va[db] = *(const short8*)&Vs[db * 16 + ll][ks * 32 + lg * 8];
#pragma unroll
            for (int rb = 0; rb < 2; rb++)
#pragma unroll
                for (int db = 0; db < 4; db++)
                    o_t[rb][db] = __builtin_amdgcn_mfma_f32_16x16x32_bf16(va[db], pa[rb], o_t[rb][db], 0, 0, 0);
        }
    }

    const int b = bh >> 4, h = bh & 15;
#pragma unroll
    for (int rb = 0; rb < 2; rb++) {
        float linv = 1.f / lrun[rb];
#pragma unroll
        for (int db = 0; db < 4; db++) {
            uint2 pw;
            pw.x = cvtpk(o_t[rb][db][0] * linv, o_t[rb][db][1] * linv);
            pw.y = cvtpk(o_t[rb][db][2] * linv, o_t[rb][db][3] * linv);
            *(uint2*)&Pl[wq + rb * 16 + ll][db * 16 + lg * 4] = pw;
        }
    }
    asm volatile("s_waitcnt lgkmcnt(0)" ::: "memory");
    __builtin_amdgcn_sched_barrier(0);
#pragma unroll
    for (int rb = 0; rb < 2; rb++)
#pragma unroll
        for (int half = 0; half < 2; half++) {
            short8 v = *(const short8*)&Pl[wq + rb * 16 + ll][half * 32 + lg * 8];
            size_t row = (size_t)(b * TSEQ + q0 + wq + rb * 16 + ll);
            *(short8*)(ctx + (row * NH + h) * HD + half * 32 + lg * 8) = v;
        }
}

extern "C" void kernel_launch(void* const* d_in, const int* in_sizes, int n_in,
                              void* d_out, int out_size, void* d_ws, size_t ws_size,
                              hipStream_t stream) {
    const float* x  = (const float*)d_in[0];
    const float* Wq = (const float*)d_in[1];
    const float* Wk = (const float*)d_in[2];
    const float* Wv = (const float*)d_in[3];
    const float* Wo = (const float*)d_in[4];
    const float* bo = (const float*)d_in[5];
    float* out = (float*)d_out;

    char* ws = (char*)d_ws;
    unsigned short* xb   = (unsigned short*)(ws);             // 16,777,216 B
    unsigned short* Wqb  = (unsigned short*)(ws + 16777216);
    unsigned short* Wkb  = (unsigned short*)(ws + 18874368);
    unsigned short* Wvb  = (unsigned short*)(ws + 20971520);
    unsigned short* Wob  = (unsigned short*)(ws + 23068672);
    unsigned short* Qb   = (unsigned short*)(ws + 25165824);  // [B,H,T,hd] bf16 (pre-scaled)
    unsigned short* Kb   = (unsigned short*)(ws + 41943040);  // [B,H,T,hd]
    unsigned short* Vtb  = (unsigned short*)(ws + 58720256);  // [B,H,hd,T]
    unsigned short* ctxb = (unsigned short*)(ws + 75497472);  // [B,T,H,hd]

    cast_f32_bf16<<<8192, 256, 0, stream>>>(x, xb, 2097152);
    cast_weights<<<4096, 256, 0, stream>>>(Wq, Wk, Wv, Wo, Wqb, Wkb, Wvb, Wob);

    gemm_qkv<<<dim3(32, 8, 3), 512, 0, stream>>>(xb, Wqb, Wkb, Wvb, Qb, Kb, Vtb);
    attn<<<dim3(64, 8), 512, 0, stream>>>(Qb, Kb, Vtb, ctxb);
    gemm_out<<<dim3(32, 8), 512, 0, stream>>>(ctxb, Wob, bo, out);
}